// Round 9
// baseline (298.270 us; speedup 1.0000x reference)
//
#include <hip/hip_runtime.h>
#include <hip/hip_bf16.h>

constexpr int NN = 100000;   // nodes
constexpr int NE = 3200000;  // edges
constexpr int BSHIFT = 8;                       // 256 dsts per bucket
constexpr int BSPAN  = 1 << BSHIFT;
constexpr int NB = (NN + BSPAN - 1) >> BSHIFT;  // 391 buckets
constexpr int CAP = 9216;                       // mean 8192 + 11 sigma; mult of 8
constexpr int NBLK = 128;                       // bucket-pass blocks: 64-edge (512B)
                                                // per-(block,bucket) segments keep
                                                // write-line amplification ~1.25x
constexpr int CHUNK = (NE + NBLK - 1) / NBLK;   // 25000 edges per block
constexpr int SLOTS = CAP / 1024;               // 9 register-held edges/thread in k_sort

// ---------------------------------------------------------------------------
// Pass A: coarse bucket sort by dst>>8.
// Payload: int2 { (dst&255)<<17 | src , bits(w) }.  (src<2^17, dl<2^8)
// ---------------------------------------------------------------------------
__global__ __launch_bounds__(256) void k_bucket(
    const int* __restrict__ ei, const float* __restrict__ ew,
    int* __restrict__ gcursor, int2* __restrict__ e_sw)
{
    __shared__ int h[NB];
    __shared__ int base[NB];
    int tid = threadIdx.x;
    int e0 = blockIdx.x * CHUNK;
    int e1 = e0 + CHUNK; if (e1 > NE) e1 = NE;
    for (int b = tid; b < NB; b += 256) h[b] = 0;
    __syncthreads();
    for (int e = e0 + tid; e < e1; e += 256)
        atomicAdd(&h[ei[NE + e] >> BSHIFT], 1);
    __syncthreads();
    for (int b = tid; b < NB; b += 256) {
        int c = h[b];
        base[b] = c ? atomicAdd(&gcursor[b], c) : 0;
    }
    __syncthreads();
    for (int e = e0 + tid; e < e1; e += 256) {
        int d = ei[NE + e];
        int b = d >> BSHIFT;
        int p = atomicAdd(&base[b], 1);
        int2 v;
        v.x = ((d & (BSPAN - 1)) << 17) | ei[e];
        v.y = __float_as_int(ew[e]);
        e_sw[(size_t)b * CAP + p] = v;
    }
}

// ---------------------------------------------------------------------------
// Pass B: within-bucket counting sort by dl, IN PLACE, edges held in
// registers (statically indexed -> VGPRs). LDS = 3KB counters.
// Emits rowptr2[d] = {beg, end} (absolute indices into e_sw).
// ---------------------------------------------------------------------------
__global__ __launch_bounds__(1024) void k_sort(
    const int* __restrict__ gcursor, int2* __restrict__ e_sw,
    int2* __restrict__ rowptr2)
{
    __shared__ int hist[BSPAN];
    __shared__ int startp[BSPAN];
    __shared__ int off[BSPAN];
    int b = blockIdx.x, tid = threadIdx.x;
    int cnt = gcursor[b];
    int2* es = e_sw + (size_t)b * CAP;
    if (tid < BSPAN) hist[tid] = 0;
    __syncthreads();
    int2 held[SLOTS];
#pragma unroll
    for (int k = 0; k < SLOTS; ++k) {
        int i = tid + k * 1024;
        if (i < cnt) {
            int2 v = es[i];
            held[k] = v;
            atomicAdd(&hist[v.x >> 17], 1);
        }
    }
    __syncthreads();
    if (tid < BSPAN) startp[tid] = hist[tid];
    __syncthreads();
    for (int o = 1; o < BSPAN; o <<= 1) {
        int v = (tid < BSPAN && tid >= o) ? startp[tid - o] : 0;
        __syncthreads();
        if (tid < BSPAN) startp[tid] += v;   // inclusive scan
        __syncthreads();
    }
    // exclusive start of dl = startp[dl] - hist[dl]
    int d0 = b << BSHIFT;
    if (tid < BSPAN) {
        int beg_rel = startp[tid] - hist[tid];
        off[tid] = beg_rel;
        int d = d0 + tid;
        if (d < NN) {
            int beg = b * CAP + beg_rel;
            int2 rp; rp.x = beg; rp.y = beg + hist[tid];
            rowptr2[d] = rp;
        }
    }
    __syncthreads();
#pragma unroll
    for (int k = 0; k < SLOTS; ++k) {
        int i = tid + k * 1024;
        if (i < cnt) {
            int2 v = held[k];
            int p = atomicAdd(&off[v.x >> 17], 1);
            es[p] = v;
        }
    }
}

// ---------------------------------------------------------------------------
// y1 = x @ W1_rel.T   (N x 64 -> N x 32); one thread per node.
// ---------------------------------------------------------------------------
__global__ __launch_bounds__(256) void k_transform1(
    const float* __restrict__ x, const float* __restrict__ W1_rel,
    float* __restrict__ y1)
{
    int n = blockIdx.x * 256 + threadIdx.x;
    if (n >= NN) return;
    float xr[64];
    const float4* xrow = reinterpret_cast<const float4*>(x + (size_t)n * 64);
#pragma unroll
    for (int i = 0; i < 16; ++i) {
        float4 v = xrow[i];
        xr[4*i+0] = v.x; xr[4*i+1] = v.y; xr[4*i+2] = v.z; xr[4*i+3] = v.w;
    }
    float4* out = reinterpret_cast<float4*>(y1 + (size_t)n * 32);
#pragma unroll
    for (int og = 0; og < 8; ++og) {
        float a[4];
#pragma unroll
        for (int j = 0; j < 4; ++j) {
            const float* wrow = W1_rel + (og * 4 + j) * 64;
            float s = 0.f;
#pragma unroll
            for (int k = 0; k < 64; ++k) s += xr[k] * wrow[k];
            a[j] = s;
        }
        float4 v; v.x = a[0]; v.y = a[1]; v.z = a[2]; v.w = a[3];
        out[og] = v;
    }
}

// ---------------------------------------------------------------------------
// Reduce pass 1: 8 lanes per dst row; register accumulation; 4-edge unroll
// with zero-weight tail masking. No LDS, no atomics.
// ---------------------------------------------------------------------------
__global__ __launch_bounds__(256) void k_reduce1(
    const int2* __restrict__ rowptr2, const int2* __restrict__ e_sw,
    const float* __restrict__ y1, float* __restrict__ agg1)
{
    int idx = blockIdx.x * 256 + threadIdx.x;
    int d = idx >> 3;
    if (d >= NN) return;
    int g = idx & 7;
    int2 rp = rowptr2[d];
    int beg = rp.x, end = rp.y;
    float a0 = 0.f, a1 = 0.f, a2 = 0.f, a3 = 0.f;
    for (int e = beg; e < end; e += 4) {
        int eB = e + 1, eC = e + 2, eD = e + 3;
        int lim = end - 1;
        int2 pA = e_sw[e];
        int2 pB = e_sw[eB < lim ? eB : lim];
        int2 pC = e_sw[eC < lim ? eC : lim];
        int2 pD = e_sw[eD < lim ? eD : lim];
        float wA = __int_as_float(pA.y);
        float wB = eB < end ? __int_as_float(pB.y) : 0.f;
        float wC = eC < end ? __int_as_float(pC.y) : 0.f;
        float wD = eD < end ? __int_as_float(pD.y) : 0.f;
        float4 vA = *reinterpret_cast<const float4*>(y1 + (size_t)(pA.x & 0x1FFFF) * 32 + g * 4);
        float4 vB = *reinterpret_cast<const float4*>(y1 + (size_t)(pB.x & 0x1FFFF) * 32 + g * 4);
        float4 vC = *reinterpret_cast<const float4*>(y1 + (size_t)(pC.x & 0x1FFFF) * 32 + g * 4);
        float4 vD = *reinterpret_cast<const float4*>(y1 + (size_t)(pD.x & 0x1FFFF) * 32 + g * 4);
        a0 += vA.x * wA + vB.x * wB + vC.x * wC + vD.x * wD;
        a1 += vA.y * wA + vB.y * wB + vC.y * wC + vD.y * wD;
        a2 += vA.z * wA + vB.z * wB + vC.z * wC + vD.z * wD;
        a3 += vA.w * wA + vB.w * wB + vC.w * wC + vD.w * wD;
    }
    float4 o; o.x = a0; o.y = a1; o.z = a2; o.w = a3;
    *reinterpret_cast<float4*>(agg1 + (size_t)d * 32 + g * 4) = o;
}

// ---------------------------------------------------------------------------
// h = relu(agg1 + b1 + x @ W1_root.T); y2 = h @ W2_rel.T; r2 = h @ W2_root.T
// ---------------------------------------------------------------------------
__global__ __launch_bounds__(256) void k_node1(
    const float* __restrict__ x, const float* __restrict__ agg1,
    const float* __restrict__ W1_root, const float* __restrict__ b1,
    const float* __restrict__ W2_rel, const float* __restrict__ W2_root,
    float* __restrict__ y2, float* __restrict__ r2)
{
    int n = blockIdx.x * 256 + threadIdx.x;
    if (n >= NN) return;
    float xr[64];
    const float4* xrow = reinterpret_cast<const float4*>(x + (size_t)n * 64);
#pragma unroll
    for (int i = 0; i < 16; ++i) {
        float4 v = xrow[i];
        xr[4*i+0] = v.x; xr[4*i+1] = v.y; xr[4*i+2] = v.z; xr[4*i+3] = v.w;
    }
    float h[32];
    const float4* arow = reinterpret_cast<const float4*>(agg1 + (size_t)n * 32);
#pragma unroll
    for (int og = 0; og < 8; ++og) {
        float4 v = arow[og];
        h[og*4+0] = v.x; h[og*4+1] = v.y; h[og*4+2] = v.z; h[og*4+3] = v.w;
    }
#pragma unroll
    for (int o = 0; o < 32; ++o) {
        const float* wrow = W1_root + o * 64;
        float ssum = 0.f;
#pragma unroll
        for (int k = 0; k < 64; ++k) ssum += xr[k] * wrow[k];
        float t = h[o] + b1[o] + ssum;
        h[o] = t > 0.f ? t : 0.f;
    }
    float o2[8], o3[8];
#pragma unroll
    for (int j = 0; j < 8; ++j) {
        const float* wr = W2_rel  + j * 32;
        const float* wo = W2_root + j * 32;
        float s0 = 0.f, s1 = 0.f;
#pragma unroll
        for (int c = 0; c < 32; ++c) { s0 += h[c] * wr[c]; s1 += h[c] * wo[c]; }
        o2[j] = s0; o3[j] = s1;
    }
    float4* y2o = reinterpret_cast<float4*>(y2 + (size_t)n * 8);
    float4* r2o = reinterpret_cast<float4*>(r2 + (size_t)n * 8);
    float4 v0, v1;
    v0.x=o2[0]; v0.y=o2[1]; v0.z=o2[2]; v0.w=o2[3]; y2o[0]=v0;
    v1.x=o2[4]; v1.y=o2[5]; v1.z=o2[6]; v1.w=o2[7]; y2o[1]=v1;
    v0.x=o3[0]; v0.y=o3[1]; v0.z=o3[2]; v0.w=o3[3]; r2o[0]=v0;
    v1.x=o3[4]; v1.y=o3[5]; v1.z=o3[6]; v1.w=o3[7]; r2o[1]=v1;
}

// ---------------------------------------------------------------------------
// Reduce pass 2: 2 lanes per dst row (8 features); register accumulation;
// 4-edge unroll with zero-weight tail masking.
// ---------------------------------------------------------------------------
__global__ __launch_bounds__(256) void k_reduce2(
    const int2* __restrict__ rowptr2, const int2* __restrict__ e_sw,
    const float* __restrict__ y2, float* __restrict__ agg2)
{
    int idx = blockIdx.x * 256 + threadIdx.x;
    int d = idx >> 1;
    if (d >= NN) return;
    int g = idx & 1;
    int2 rp = rowptr2[d];
    int beg = rp.x, end = rp.y;
    float a0 = 0.f, a1 = 0.f, a2 = 0.f, a3 = 0.f;
    for (int e = beg; e < end; e += 4) {
        int eB = e + 1, eC = e + 2, eD = e + 3;
        int lim = end - 1;
        int2 pA = e_sw[e];
        int2 pB = e_sw[eB < lim ? eB : lim];
        int2 pC = e_sw[eC < lim ? eC : lim];
        int2 pD = e_sw[eD < lim ? eD : lim];
        float wA = __int_as_float(pA.y);
        float wB = eB < end ? __int_as_float(pB.y) : 0.f;
        float wC = eC < end ? __int_as_float(pC.y) : 0.f;
        float wD = eD < end ? __int_as_float(pD.y) : 0.f;
        float4 vA = *reinterpret_cast<const float4*>(y2 + (size_t)(pA.x & 0x1FFFF) * 8 + g * 4);
        float4 vB = *reinterpret_cast<const float4*>(y2 + (size_t)(pB.x & 0x1FFFF) * 8 + g * 4);
        float4 vC = *reinterpret_cast<const float4*>(y2 + (size_t)(pC.x & 0x1FFFF) * 8 + g * 4);
        float4 vD = *reinterpret_cast<const float4*>(y2 + (size_t)(pD.x & 0x1FFFF) * 8 + g * 4);
        a0 += vA.x * wA + vB.x * wB + vC.x * wC + vD.x * wD;
        a1 += vA.y * wA + vB.y * wB + vC.y * wC + vD.y * wD;
        a2 += vA.z * wA + vB.z * wB + vC.z * wC + vD.z * wD;
        a3 += vA.w * wA + vB.w * wB + vC.w * wC + vD.w * wD;
    }
    float4 o; o.x = a0; o.y = a1; o.z = a2; o.w = a3;
    *reinterpret_cast<float4*>(agg2 + (size_t)d * 8 + g * 4) = o;
}

// ---------------------------------------------------------------------------
// Final: h2 = agg2 + b2 + r2; emb = log_softmax(h2); out = relu([emb,x1]@W_lin.T+b)
// ---------------------------------------------------------------------------
__global__ __launch_bounds__(256) void k_final(
    const float* __restrict__ agg2, const float* __restrict__ r2,
    const float* __restrict__ x1, const float* __restrict__ b2,
    const float* __restrict__ W_lin, const float* __restrict__ b_lin,
    float* __restrict__ outv, float* __restrict__ emb)
{
    int n = blockIdx.x * 256 + threadIdx.x;
    if (n >= NN) return;
    const float4* arow = reinterpret_cast<const float4*>(agg2 + (size_t)n * 8);
    const float4* rrow = reinterpret_cast<const float4*>(r2   + (size_t)n * 8);
    float h2[8];
    {
        float4 a0 = arow[0], a1 = arow[1], r0 = rrow[0], r1 = rrow[1];
        h2[0]=a0.x+r0.x+b2[0]; h2[1]=a0.y+r0.y+b2[1];
        h2[2]=a0.z+r0.z+b2[2]; h2[3]=a0.w+r0.w+b2[3];
        h2[4]=a1.x+r1.x+b2[4]; h2[5]=a1.y+r1.y+b2[5];
        h2[6]=a1.z+r1.z+b2[6]; h2[7]=a1.w+r1.w+b2[7];
    }
    float m = h2[0];
#pragma unroll
    for (int j = 1; j < 8; ++j) m = fmaxf(m, h2[j]);
    float sum = 0.f;
#pragma unroll
    for (int j = 0; j < 8; ++j) sum += __expf(h2[j] - m);
    float lse = __logf(sum);
    float eb[8];
#pragma unroll
    for (int j = 0; j < 8; ++j) eb[j] = h2[j] - m - lse;
    float4* eo = reinterpret_cast<float4*>(emb + (size_t)n * 8);
    float4 v0, v1;
    v0.x=eb[0]; v0.y=eb[1]; v0.z=eb[2]; v0.w=eb[3]; eo[0]=v0;
    v1.x=eb[4]; v1.y=eb[5]; v1.z=eb[6]; v1.w=eb[7]; eo[1]=v1;
    float acc = b_lin[0] + x1[n] * W_lin[8];
#pragma unroll
    for (int j = 0; j < 8; ++j) acc += eb[j] * W_lin[j];
    outv[n] = acc > 0.f ? acc : 0.f;
}

// ---------------------------------------------------------------------------
extern "C" void kernel_launch(void* const* d_in, const int* in_sizes, int n_in,
                              void* d_out, int out_size, void* d_ws, size_t ws_size,
                              hipStream_t stream) {
    const float* x      = (const float*)d_in[0];
    const int*   ei     = (const int*)  d_in[1];
    const float* ew     = (const float*)d_in[2];
    const float* x1     = (const float*)d_in[3];
    const float* W1_rel = (const float*)d_in[4];
    const float* b1     = (const float*)d_in[5];
    const float* W1_root= (const float*)d_in[6];
    const float* W2_rel = (const float*)d_in[7];
    const float* b2     = (const float*)d_in[8];
    const float* W2_root= (const float*)d_in[9];
    const float* W_lin  = (const float*)d_in[10];
    const float* b_lin  = (const float*)d_in[11];

    float* ws    = (float*)d_ws;
    float* y1    = ws;                           // N*32
    float* agg1  = y1   + (size_t)NN * 32;       // N*32
    float* y2    = agg1 + (size_t)NN * 32;       // N*8
    float* r2    = y2   + (size_t)NN * 8;        // N*8
    float* agg2  = r2   + (size_t)NN * 8;        // N*8
    int*   gcursor = (int*)(agg2 + (size_t)NN * 8);     // NB, padded to 1024
    int2*  rowptr2 = (int2*)(gcursor + 1024);           // NN int2
    int2*  e_sw    = rowptr2 + NN;                      // NB*CAP int2 (64B-aligned)

    float* outv = (float*)d_out;             // N   (output 0)
    float* emb  = outv + NN;                 // N*8 (output 1)

    hipMemsetAsync(gcursor, 0, NB * sizeof(int), stream);

    int nbN = (NN + 255) / 256;
    k_bucket<<<NBLK, 256, 0, stream>>>(ei, ew, gcursor, e_sw);
    k_sort<<<NB, 1024, 0, stream>>>(gcursor, e_sw, rowptr2);
    k_transform1<<<nbN, 256, 0, stream>>>(x, W1_rel, y1);
    k_reduce1<<<(NN * 8 + 255) / 256, 256, 0, stream>>>(rowptr2, e_sw, y1, agg1);
    k_node1<<<nbN, 256, 0, stream>>>(x, agg1, W1_root, b1, W2_rel, W2_root, y2, r2);
    k_reduce2<<<(NN * 2 + 255) / 256, 256, 0, stream>>>(rowptr2, e_sw, y2, agg2);
    k_final<<<nbN, 256, 0, stream>>>(agg2, r2, x1, b2, W_lin, b_lin, outv, emb);
}

// Round 10
// 250.717 us; speedup vs baseline: 1.1897x; 1.1897x over previous
//
#include <hip/hip_runtime.h>
#include <hip/hip_bf16.h>

constexpr int NN = 100000;   // nodes
constexpr int NE = 3200000;  // edges
constexpr int BSHIFT = 8;                       // 256 dsts per bucket
constexpr int BSPAN  = 1 << BSHIFT;
constexpr int NB = (NN + BSPAN - 1) >> BSHIFT;  // 391 buckets
constexpr int CAP = 12288;                      // mean 8184 real + mean 1792 pad, +22sigma; mult of 8
constexpr int NBLK = 512;                       // bucket-pass blocks (2/CU for store-latency hiding)
constexpr int CHUNK = (NE + NBLK - 1) / NBLK;   // 6250 edges per block
constexpr int SLOTS = CAP / 1024;               // 12 register-held edges/thread in k_sort

// ---------------------------------------------------------------------------
// Pass A: coarse bucket sort by dst>>8 with 64B-ALIGNED BLOCK-EXCLUSIVE
// segments: each block reserves round8(count) slots per bucket, pads the
// tail with sentinel edges {x=-1, w=0}. No cache line is shared between
// blocks -> full-line writebacks, no cross-XCD partial-line RMW.
// Payload: int2 { (dst&255)<<17 | src , bits(w) }.  (src<2^17, dl<2^8)
// ---------------------------------------------------------------------------
__global__ __launch_bounds__(256) void k_bucket(
    const int* __restrict__ ei, const float* __restrict__ ew,
    int* __restrict__ gcursor, int2* __restrict__ e_sw)
{
    __shared__ int h[NB];
    __shared__ int base[NB];
    __shared__ int pend[NB];
    int tid = threadIdx.x;
    int e0 = blockIdx.x * CHUNK;
    int e1 = e0 + CHUNK; if (e1 > NE) e1 = NE;
    for (int b = tid; b < NB; b += 256) h[b] = 0;
    __syncthreads();
    for (int e = e0 + tid; e < e1; e += 256)
        atomicAdd(&h[ei[NE + e] >> BSHIFT], 1);
    __syncthreads();
    for (int b = tid; b < NB; b += 256) {
        int c = h[b];
        int r = (c + 7) & ~7;                    // 64B-aligned reservation
        int bs = r ? atomicAdd(&gcursor[b], r) : 0;
        base[b] = bs;
        pend[b] = bs + r;
    }
    __syncthreads();
    for (int e = e0 + tid; e < e1; e += 256) {
        int d = ei[NE + e];
        int b = d >> BSHIFT;
        int p = atomicAdd(&base[b], 1);
        int2 v;
        v.x = ((d & (BSPAN - 1)) << 17) | ei[e];
        v.y = __float_as_int(ew[e]);
        e_sw[(size_t)b * CAP + p] = v;
    }
    __syncthreads();
    // pad each owned segment to its 8-slot boundary with sentinels
    int2 sv; sv.x = -1; sv.y = 0;
    for (int b = tid; b < NB; b += 256) {
        for (int p = base[b]; p < pend[b]; ++p)
            e_sw[(size_t)b * CAP + p] = sv;
    }
}

// ---------------------------------------------------------------------------
// Pass B: within-bucket counting sort by dl, IN PLACE, edges held in
// registers (statically indexed -> VGPRs). Sentinels (x<0) are skipped:
// they never reach the reduce kernels. LDS = 3KB counters.
// Emits rowptr2[d] = {beg, end} (absolute indices into e_sw, real edges only).
// ---------------------------------------------------------------------------
__global__ __launch_bounds__(1024) void k_sort(
    const int* __restrict__ gcursor, int2* __restrict__ e_sw,
    int2* __restrict__ rowptr2)
{
    __shared__ int hist[BSPAN];
    __shared__ int startp[BSPAN];
    __shared__ int off[BSPAN];
    int b = blockIdx.x, tid = threadIdx.x;
    int cnt = gcursor[b];                 // padded count (incl. sentinels)
    int2* es = e_sw + (size_t)b * CAP;
    if (tid < BSPAN) hist[tid] = 0;
    __syncthreads();
    int2 held[SLOTS];
#pragma unroll
    for (int k = 0; k < SLOTS; ++k) {
        int i = tid + k * 1024;
        held[k].x = -1;
        if (i < cnt) {
            int2 v = es[i];
            held[k] = v;
            if (v.x >= 0) atomicAdd(&hist[v.x >> 17], 1);
        }
    }
    __syncthreads();
    if (tid < BSPAN) startp[tid] = hist[tid];
    __syncthreads();
    for (int o = 1; o < BSPAN; o <<= 1) {
        int v = (tid < BSPAN && tid >= o) ? startp[tid - o] : 0;
        __syncthreads();
        if (tid < BSPAN) startp[tid] += v;   // inclusive scan
        __syncthreads();
    }
    // exclusive start of dl = startp[dl] - hist[dl]
    int d0 = b << BSHIFT;
    if (tid < BSPAN) {
        int beg_rel = startp[tid] - hist[tid];
        off[tid] = beg_rel;
        int d = d0 + tid;
        if (d < NN) {
            int beg = b * CAP + beg_rel;
            int2 rp; rp.x = beg; rp.y = beg + hist[tid];
            rowptr2[d] = rp;
        }
    }
    __syncthreads();
#pragma unroll
    for (int k = 0; k < SLOTS; ++k) {
        int2 v = held[k];
        if (v.x >= 0) {
            int p = atomicAdd(&off[v.x >> 17], 1);
            es[p] = v;
        }
    }
}

// ---------------------------------------------------------------------------
// y1 = x @ W1_rel.T   (N x 64 -> N x 32); one thread per node.
// ---------------------------------------------------------------------------
__global__ __launch_bounds__(256) void k_transform1(
    const float* __restrict__ x, const float* __restrict__ W1_rel,
    float* __restrict__ y1)
{
    int n = blockIdx.x * 256 + threadIdx.x;
    if (n >= NN) return;
    float xr[64];
    const float4* xrow = reinterpret_cast<const float4*>(x + (size_t)n * 64);
#pragma unroll
    for (int i = 0; i < 16; ++i) {
        float4 v = xrow[i];
        xr[4*i+0] = v.x; xr[4*i+1] = v.y; xr[4*i+2] = v.z; xr[4*i+3] = v.w;
    }
    float4* out = reinterpret_cast<float4*>(y1 + (size_t)n * 32);
#pragma unroll
    for (int og = 0; og < 8; ++og) {
        float a[4];
#pragma unroll
        for (int j = 0; j < 4; ++j) {
            const float* wrow = W1_rel + (og * 4 + j) * 64;
            float s = 0.f;
#pragma unroll
            for (int k = 0; k < 64; ++k) s += xr[k] * wrow[k];
            a[j] = s;
        }
        float4 v; v.x = a[0]; v.y = a[1]; v.z = a[2]; v.w = a[3];
        out[og] = v;
    }
}

// ---------------------------------------------------------------------------
// Reduce pass 1: 8 lanes per dst row; register accumulation; 4-edge unroll
// with zero-weight tail masking. No LDS, no atomics.
// ---------------------------------------------------------------------------
__global__ __launch_bounds__(256) void k_reduce1(
    const int2* __restrict__ rowptr2, const int2* __restrict__ e_sw,
    const float* __restrict__ y1, float* __restrict__ agg1)
{
    int idx = blockIdx.x * 256 + threadIdx.x;
    int d = idx >> 3;
    if (d >= NN) return;
    int g = idx & 7;
    int2 rp = rowptr2[d];
    int beg = rp.x, end = rp.y;
    float a0 = 0.f, a1 = 0.f, a2 = 0.f, a3 = 0.f;
    for (int e = beg; e < end; e += 4) {
        int eB = e + 1, eC = e + 2, eD = e + 3;
        int lim = end - 1;
        int2 pA = e_sw[e];
        int2 pB = e_sw[eB < lim ? eB : lim];
        int2 pC = e_sw[eC < lim ? eC : lim];
        int2 pD = e_sw[eD < lim ? eD : lim];
        float wA = __int_as_float(pA.y);
        float wB = eB < end ? __int_as_float(pB.y) : 0.f;
        float wC = eC < end ? __int_as_float(pC.y) : 0.f;
        float wD = eD < end ? __int_as_float(pD.y) : 0.f;
        float4 vA = *reinterpret_cast<const float4*>(y1 + (size_t)(pA.x & 0x1FFFF) * 32 + g * 4);
        float4 vB = *reinterpret_cast<const float4*>(y1 + (size_t)(pB.x & 0x1FFFF) * 32 + g * 4);
        float4 vC = *reinterpret_cast<const float4*>(y1 + (size_t)(pC.x & 0x1FFFF) * 32 + g * 4);
        float4 vD = *reinterpret_cast<const float4*>(y1 + (size_t)(pD.x & 0x1FFFF) * 32 + g * 4);
        a0 += vA.x * wA + vB.x * wB + vC.x * wC + vD.x * wD;
        a1 += vA.y * wA + vB.y * wB + vC.y * wC + vD.y * wD;
        a2 += vA.z * wA + vB.z * wB + vC.z * wC + vD.z * wD;
        a3 += vA.w * wA + vB.w * wB + vC.w * wC + vD.w * wD;
    }
    float4 o; o.x = a0; o.y = a1; o.z = a2; o.w = a3;
    *reinterpret_cast<float4*>(agg1 + (size_t)d * 32 + g * 4) = o;
}

// ---------------------------------------------------------------------------
// h = relu(agg1 + b1 + x @ W1_root.T); y2 = h @ W2_rel.T; r2 = h @ W2_root.T
// ---------------------------------------------------------------------------
__global__ __launch_bounds__(256) void k_node1(
    const float* __restrict__ x, const float* __restrict__ agg1,
    const float* __restrict__ W1_root, const float* __restrict__ b1,
    const float* __restrict__ W2_rel, const float* __restrict__ W2_root,
    float* __restrict__ y2, float* __restrict__ r2)
{
    int n = blockIdx.x * 256 + threadIdx.x;
    if (n >= NN) return;
    float xr[64];
    const float4* xrow = reinterpret_cast<const float4*>(x + (size_t)n * 64);
#pragma unroll
    for (int i = 0; i < 16; ++i) {
        float4 v = xrow[i];
        xr[4*i+0] = v.x; xr[4*i+1] = v.y; xr[4*i+2] = v.z; xr[4*i+3] = v.w;
    }
    float h[32];
    const float4* arow = reinterpret_cast<const float4*>(agg1 + (size_t)n * 32);
#pragma unroll
    for (int og = 0; og < 8; ++og) {
        float4 v = arow[og];
        h[og*4+0] = v.x; h[og*4+1] = v.y; h[og*4+2] = v.z; h[og*4+3] = v.w;
    }
#pragma unroll
    for (int o = 0; o < 32; ++o) {
        const float* wrow = W1_root + o * 64;
        float ssum = 0.f;
#pragma unroll
        for (int k = 0; k < 64; ++k) ssum += xr[k] * wrow[k];
        float t = h[o] + b1[o] + ssum;
        h[o] = t > 0.f ? t : 0.f;
    }
    float o2[8], o3[8];
#pragma unroll
    for (int j = 0; j < 8; ++j) {
        const float* wr = W2_rel  + j * 32;
        const float* wo = W2_root + j * 32;
        float s0 = 0.f, s1 = 0.f;
#pragma unroll
        for (int c = 0; c < 32; ++c) { s0 += h[c] * wr[c]; s1 += h[c] * wo[c]; }
        o2[j] = s0; o3[j] = s1;
    }
    float4* y2o = reinterpret_cast<float4*>(y2 + (size_t)n * 8);
    float4* r2o = reinterpret_cast<float4*>(r2 + (size_t)n * 8);
    float4 v0, v1;
    v0.x=o2[0]; v0.y=o2[1]; v0.z=o2[2]; v0.w=o2[3]; y2o[0]=v0;
    v1.x=o2[4]; v1.y=o2[5]; v1.z=o2[6]; v1.w=o2[7]; y2o[1]=v1;
    v0.x=o3[0]; v0.y=o3[1]; v0.z=o3[2]; v0.w=o3[3]; r2o[0]=v0;
    v1.x=o3[4]; v1.y=o3[5]; v1.z=o3[6]; v1.w=o3[7]; r2o[1]=v1;
}

// ---------------------------------------------------------------------------
// Reduce pass 2: 2 lanes per dst row (8 features); register accumulation;
// 4-edge unroll with zero-weight tail masking.
// ---------------------------------------------------------------------------
__global__ __launch_bounds__(256) void k_reduce2(
    const int2* __restrict__ rowptr2, const int2* __restrict__ e_sw,
    const float* __restrict__ y2, float* __restrict__ agg2)
{
    int idx = blockIdx.x * 256 + threadIdx.x;
    int d = idx >> 1;
    if (d >= NN) return;
    int g = idx & 1;
    int2 rp = rowptr2[d];
    int beg = rp.x, end = rp.y;
    float a0 = 0.f, a1 = 0.f, a2 = 0.f, a3 = 0.f;
    for (int e = beg; e < end; e += 4) {
        int eB = e + 1, eC = e + 2, eD = e + 3;
        int lim = end - 1;
        int2 pA = e_sw[e];
        int2 pB = e_sw[eB < lim ? eB : lim];
        int2 pC = e_sw[eC < lim ? eC : lim];
        int2 pD = e_sw[eD < lim ? eD : lim];
        float wA = __int_as_float(pA.y);
        float wB = eB < end ? __int_as_float(pB.y) : 0.f;
        float wC = eC < end ? __int_as_float(pC.y) : 0.f;
        float wD = eD < end ? __int_as_float(pD.y) : 0.f;
        float4 vA = *reinterpret_cast<const float4*>(y2 + (size_t)(pA.x & 0x1FFFF) * 8 + g * 4);
        float4 vB = *reinterpret_cast<const float4*>(y2 + (size_t)(pB.x & 0x1FFFF) * 8 + g * 4);
        float4 vC = *reinterpret_cast<const float4*>(y2 + (size_t)(pC.x & 0x1FFFF) * 8 + g * 4);
        float4 vD = *reinterpret_cast<const float4*>(y2 + (size_t)(pD.x & 0x1FFFF) * 8 + g * 4);
        a0 += vA.x * wA + vB.x * wB + vC.x * wC + vD.x * wD;
        a1 += vA.y * wA + vB.y * wB + vC.y * wC + vD.y * wD;
        a2 += vA.z * wA + vB.z * wB + vC.z * wC + vD.z * wD;
        a3 += vA.w * wA + vB.w * wB + vC.w * wC + vD.w * wD;
    }
    float4 o; o.x = a0; o.y = a1; o.z = a2; o.w = a3;
    *reinterpret_cast<float4*>(agg2 + (size_t)d * 8 + g * 4) = o;
}

// ---------------------------------------------------------------------------
// Final: h2 = agg2 + b2 + r2; emb = log_softmax(h2); out = relu([emb,x1]@W_lin.T+b)
// ---------------------------------------------------------------------------
__global__ __launch_bounds__(256) void k_final(
    const float* __restrict__ agg2, const float* __restrict__ r2,
    const float* __restrict__ x1, const float* __restrict__ b2,
    const float* __restrict__ W_lin, const float* __restrict__ b_lin,
    float* __restrict__ outv, float* __restrict__ emb)
{
    int n = blockIdx.x * 256 + threadIdx.x;
    if (n >= NN) return;
    const float4* arow = reinterpret_cast<const float4*>(agg2 + (size_t)n * 8);
    const float4* rrow = reinterpret_cast<const float4*>(r2   + (size_t)n * 8);
    float h2[8];
    {
        float4 a0 = arow[0], a1 = arow[1], r0 = rrow[0], r1 = rrow[1];
        h2[0]=a0.x+r0.x+b2[0]; h2[1]=a0.y+r0.y+b2[1];
        h2[2]=a0.z+r0.z+b2[2]; h2[3]=a0.w+r0.w+b2[3];
        h2[4]=a1.x+r1.x+b2[4]; h2[5]=a1.y+r1.y+b2[5];
        h2[6]=a1.z+r1.z+b2[6]; h2[7]=a1.w+r1.w+b2[7];
    }
    float m = h2[0];
#pragma unroll
    for (int j = 1; j < 8; ++j) m = fmaxf(m, h2[j]);
    float sum = 0.f;
#pragma unroll
    for (int j = 0; j < 8; ++j) sum += __expf(h2[j] - m);
    float lse = __logf(sum);
    float eb[8];
#pragma unroll
    for (int j = 0; j < 8; ++j) eb[j] = h2[j] - m - lse;
    float4* eo = reinterpret_cast<float4*>(emb + (size_t)n * 8);
    float4 v0, v1;
    v0.x=eb[0]; v0.y=eb[1]; v0.z=eb[2]; v0.w=eb[3]; eo[0]=v0;
    v1.x=eb[4]; v1.y=eb[5]; v1.z=eb[6]; v1.w=eb[7]; eo[1]=v1;
    float acc = b_lin[0] + x1[n] * W_lin[8];
#pragma unroll
    for (int j = 0; j < 8; ++j) acc += eb[j] * W_lin[j];
    outv[n] = acc > 0.f ? acc : 0.f;
}

// ---------------------------------------------------------------------------
extern "C" void kernel_launch(void* const* d_in, const int* in_sizes, int n_in,
                              void* d_out, int out_size, void* d_ws, size_t ws_size,
                              hipStream_t stream) {
    const float* x      = (const float*)d_in[0];
    const int*   ei     = (const int*)  d_in[1];
    const float* ew     = (const float*)d_in[2];
    const float* x1     = (const float*)d_in[3];
    const float* W1_rel = (const float*)d_in[4];
    const float* b1     = (const float*)d_in[5];
    const float* W1_root= (const float*)d_in[6];
    const float* W2_rel = (const float*)d_in[7];
    const float* b2     = (const float*)d_in[8];
    const float* W2_root= (const float*)d_in[9];
    const float* W_lin  = (const float*)d_in[10];
    const float* b_lin  = (const float*)d_in[11];

    float* ws    = (float*)d_ws;
    float* y1    = ws;                           // N*32
    float* agg1  = y1   + (size_t)NN * 32;       // N*32
    float* y2    = agg1 + (size_t)NN * 32;       // N*8
    float* r2    = y2   + (size_t)NN * 8;        // N*8
    float* agg2  = r2   + (size_t)NN * 8;        // N*8
    int*   gcursor = (int*)(agg2 + (size_t)NN * 8);     // NB, padded to 1024
    int2*  rowptr2 = (int2*)(gcursor + 1024);           // NN int2
    int2*  e_sw    = rowptr2 + NN;                      // NB*CAP int2 (64B-aligned)

    float* outv = (float*)d_out;             // N   (output 0)
    float* emb  = outv + NN;                 // N*8 (output 1)

    hipMemsetAsync(gcursor, 0, NB * sizeof(int), stream);

    int nbN = (NN + 255) / 256;
    k_bucket<<<NBLK, 256, 0, stream>>>(ei, ew, gcursor, e_sw);
    k_sort<<<NB, 1024, 0, stream>>>(gcursor, e_sw, rowptr2);
    k_transform1<<<nbN, 256, 0, stream>>>(x, W1_rel, y1);
    k_reduce1<<<(NN * 8 + 255) / 256, 256, 0, stream>>>(rowptr2, e_sw, y1, agg1);
    k_node1<<<nbN, 256, 0, stream>>>(x, agg1, W1_root, b1, W2_rel, W2_root, y2, r2);
    k_reduce2<<<(NN * 2 + 255) / 256, 256, 0, stream>>>(rowptr2, e_sw, y2, agg2);
    k_final<<<nbN, 256, 0, stream>>>(agg2, r2, x1, b2, W_lin, b_lin, outv, emb);
}

// Round 11
// 247.530 us; speedup vs baseline: 1.2050x; 1.0129x over previous
//
#include <hip/hip_runtime.h>
#include <hip/hip_bf16.h>

constexpr int NN = 100000;   // nodes
constexpr int NE = 3200000;  // edges
constexpr int BSHIFT = 8;                       // 256 dsts per bucket
constexpr int BSPAN  = 1 << BSHIFT;
constexpr int NB = (NN + BSPAN - 1) >> BSHIFT;  // 391 buckets
constexpr int CAP = 12288;                      // mean 8184 real + 2048 pad, +~17 sigma; CAP/1024=12
constexpr int NBLK = 256;                       // stage-and-burst blocks (1/CU, 512 thr)
constexpr int THR  = 512;
constexpr int CHUNK = NE / NBLK;                // 12500 edges per block (exact)
constexpr int SLOTS = CAP / 1024;               // 12 register-held edges/thread in k_sort

// ---------------------------------------------------------------------------
// Pass A: stage-and-burst coarse bucket sort by dst>>8.
//   1. stash whole chunk in LDS + per-bucket histogram
//   2. scan -> per-bucket local starts
//   3. reserve 128B-aligned exclusive global segments (round16 + sentinel pad)
//   4. rank: inv16[local_out_pos] = stash index
//   5. burst: write output in bucket-sorted order -> lines fill instantly,
//      no partially-dirty frontier (round-10 lesson: frontier churn, not
//      boundary sharing, caused the 3x write amplification)
// Payload: int2 { (dst&255)<<17 | src , bits(w) }; sentinel x=-1.
// ---------------------------------------------------------------------------
__global__ __launch_bounds__(THR) void k_bucket(
    const int* __restrict__ ei, const float* __restrict__ ew,
    int* __restrict__ gcursor, int2* __restrict__ e_sw)
{
    __shared__ int2 stash[CHUNK];                 // 100000 B
    __shared__ unsigned short inv16[CHUNK];       //  25000 B
    __shared__ int h[NB];
    __shared__ int scan[THR];                     // inclusive scan of h (padded)
    __shared__ int off[NB];
    __shared__ int gbase[NB];
    int tid = threadIdx.x;
    int e0 = blockIdx.x * CHUNK;

    for (int b = tid; b < NB; b += THR) h[b] = 0;
    __syncthreads();
    // phase 1: stash + histogram
#pragma unroll
    for (int k = 0; k < CHUNK / THR; ++k) {       // 25 exact (12500/500... 12500/512)
        int j = tid + k * THR;
        if (j < CHUNK) {
            int e = e0 + j;
            int d = ei[NE + e];
            int2 v;
            v.x = ((d & (BSPAN - 1)) << 17) | ei[e];
            v.y = __float_as_int(ew[e]);
            stash[j] = v;
            atomicAdd(&h[d >> BSHIFT], 1);
        }
    }
    // handle CHUNK not multiple of THR (12500 = 24*512 + 212)
    {
        int j = tid + (CHUNK / THR) * THR;
        if (j < CHUNK) {
            int e = e0 + j;
            int d = ei[NE + e];
            int2 v;
            v.x = ((d & (BSPAN - 1)) << 17) | ei[e];
            v.y = __float_as_int(ew[e]);
            stash[j] = v;
            atomicAdd(&h[d >> BSHIFT], 1);
        }
    }
    __syncthreads();
    // phase 2: inclusive scan of h over buckets (padded to THR)
    scan[tid] = (tid < NB) ? h[tid] : 0;
    __syncthreads();
    for (int o = 1; o < THR; o <<= 1) {
        int v = (tid >= o) ? scan[tid - o] : 0;
        __syncthreads();
        scan[tid] += v;
        __syncthreads();
    }
    // phase 3: reserve aligned exclusive segments; init off to excl start
    if (tid < NB) {
        int c = h[tid];
        int r = (c + 15) & ~15;                   // 128B-aligned reservation
        gbase[tid] = r ? atomicAdd(&gcursor[tid], r) : 0;
        off[tid] = scan[tid] - c;                 // exclusive local start
    }
    __syncthreads();
    // phase 4: rank — inv16[outpos] = stash index (dst re-read, L2-hot)
    for (int j = tid; j < CHUNK; j += THR) {
        int b = ei[NE + e0 + j] >> BSHIFT;
        int p = atomicAdd(&off[b], 1);
        inv16[p] = (unsigned short)j;
    }
    __syncthreads();
    // phase 5: burst in output order; bucket via binary search on scan
    for (int i = tid; i < CHUNK; i += THR) {
        int lo = 0, hi = NB - 1;
        while (lo < hi) {
            int mid = (lo + hi) >> 1;
            if (scan[mid] > i) hi = mid; else lo = mid + 1;
        }
        int b = lo;
        int rel = i - (scan[b] - h[b]);
        int2 v = stash[inv16[i]];
        e_sw[(size_t)b * CAP + gbase[b] + rel] = v;
    }
    // phase 6: pad each owned segment tail with sentinels (completes lines)
    int2 sv; sv.x = -1; sv.y = 0;
    for (int b = tid; b < NB; b += THR) {
        int c = h[b];
        int r = (c + 15) & ~15;
        for (int p = c; p < r; ++p)
            e_sw[(size_t)b * CAP + gbase[b] + p] = sv;
    }
}

// ---------------------------------------------------------------------------
// Pass B: within-bucket counting sort by dl, IN PLACE, edges held in
// registers (statically indexed -> VGPRs). Sentinels (x<0) are skipped.
// Emits rowptr2[d] = {beg, end} (absolute indices into e_sw, real edges only).
// ---------------------------------------------------------------------------
__global__ __launch_bounds__(1024) void k_sort(
    const int* __restrict__ gcursor, int2* __restrict__ e_sw,
    int2* __restrict__ rowptr2)
{
    __shared__ int hist[BSPAN];
    __shared__ int startp[BSPAN];
    __shared__ int off[BSPAN];
    int b = blockIdx.x, tid = threadIdx.x;
    int cnt = gcursor[b];                 // padded count (incl. sentinels)
    int2* es = e_sw + (size_t)b * CAP;
    if (tid < BSPAN) hist[tid] = 0;
    __syncthreads();
    int2 held[SLOTS];
#pragma unroll
    for (int k = 0; k < SLOTS; ++k) {
        int i = tid + k * 1024;
        held[k].x = -1;
        if (i < cnt) {
            int2 v = es[i];
            held[k] = v;
            if (v.x >= 0) atomicAdd(&hist[v.x >> 17], 1);
        }
    }
    __syncthreads();
    if (tid < BSPAN) startp[tid] = hist[tid];
    __syncthreads();
    for (int o = 1; o < BSPAN; o <<= 1) {
        int v = (tid < BSPAN && tid >= o) ? startp[tid - o] : 0;
        __syncthreads();
        if (tid < BSPAN) startp[tid] += v;   // inclusive scan
        __syncthreads();
    }
    int d0 = b << BSHIFT;
    if (tid < BSPAN) {
        int beg_rel = startp[tid] - hist[tid];
        off[tid] = beg_rel;
        int d = d0 + tid;
        if (d < NN) {
            int beg = b * CAP + beg_rel;
            int2 rp; rp.x = beg; rp.y = beg + hist[tid];
            rowptr2[d] = rp;
        }
    }
    __syncthreads();
#pragma unroll
    for (int k = 0; k < SLOTS; ++k) {
        int2 v = held[k];
        if (v.x >= 0) {
            int p = atomicAdd(&off[v.x >> 17], 1);
            es[p] = v;
        }
    }
}

// ---------------------------------------------------------------------------
// y1 = x @ W1_rel.T   (N x 64 -> N x 32); one thread per node.
// ---------------------------------------------------------------------------
__global__ __launch_bounds__(256) void k_transform1(
    const float* __restrict__ x, const float* __restrict__ W1_rel,
    float* __restrict__ y1)
{
    int n = blockIdx.x * 256 + threadIdx.x;
    if (n >= NN) return;
    float xr[64];
    const float4* xrow = reinterpret_cast<const float4*>(x + (size_t)n * 64);
#pragma unroll
    for (int i = 0; i < 16; ++i) {
        float4 v = xrow[i];
        xr[4*i+0] = v.x; xr[4*i+1] = v.y; xr[4*i+2] = v.z; xr[4*i+3] = v.w;
    }
    float4* out = reinterpret_cast<float4*>(y1 + (size_t)n * 32);
#pragma unroll
    for (int og = 0; og < 8; ++og) {
        float a[4];
#pragma unroll
        for (int j = 0; j < 4; ++j) {
            const float* wrow = W1_rel + (og * 4 + j) * 64;
            float s = 0.f;
#pragma unroll
            for (int k = 0; k < 64; ++k) s += xr[k] * wrow[k];
            a[j] = s;
        }
        float4 v; v.x = a[0]; v.y = a[1]; v.z = a[2]; v.w = a[3];
        out[og] = v;
    }
}

// ---------------------------------------------------------------------------
// Reduce pass 1: 8 lanes per dst row; register accumulation; 4-edge unroll
// with zero-weight tail masking. No LDS, no atomics.
// ---------------------------------------------------------------------------
__global__ __launch_bounds__(256) void k_reduce1(
    const int2* __restrict__ rowptr2, const int2* __restrict__ e_sw,
    const float* __restrict__ y1, float* __restrict__ agg1)
{
    int idx = blockIdx.x * 256 + threadIdx.x;
    int d = idx >> 3;
    if (d >= NN) return;
    int g = idx & 7;
    int2 rp = rowptr2[d];
    int beg = rp.x, end = rp.y;
    float a0 = 0.f, a1 = 0.f, a2 = 0.f, a3 = 0.f;
    for (int e = beg; e < end; e += 4) {
        int eB = e + 1, eC = e + 2, eD = e + 3;
        int lim = end - 1;
        int2 pA = e_sw[e];
        int2 pB = e_sw[eB < lim ? eB : lim];
        int2 pC = e_sw[eC < lim ? eC : lim];
        int2 pD = e_sw[eD < lim ? eD : lim];
        float wA = __int_as_float(pA.y);
        float wB = eB < end ? __int_as_float(pB.y) : 0.f;
        float wC = eC < end ? __int_as_float(pC.y) : 0.f;
        float wD = eD < end ? __int_as_float(pD.y) : 0.f;
        float4 vA = *reinterpret_cast<const float4*>(y1 + (size_t)(pA.x & 0x1FFFF) * 32 + g * 4);
        float4 vB = *reinterpret_cast<const float4*>(y1 + (size_t)(pB.x & 0x1FFFF) * 32 + g * 4);
        float4 vC = *reinterpret_cast<const float4*>(y1 + (size_t)(pC.x & 0x1FFFF) * 32 + g * 4);
        float4 vD = *reinterpret_cast<const float4*>(y1 + (size_t)(pD.x & 0x1FFFF) * 32 + g * 4);
        a0 += vA.x * wA + vB.x * wB + vC.x * wC + vD.x * wD;
        a1 += vA.y * wA + vB.y * wB + vC.y * wC + vD.y * wD;
        a2 += vA.z * wA + vB.z * wB + vC.z * wC + vD.z * wD;
        a3 += vA.w * wA + vB.w * wB + vC.w * wC + vD.w * wD;
    }
    float4 o; o.x = a0; o.y = a1; o.z = a2; o.w = a3;
    *reinterpret_cast<float4*>(agg1 + (size_t)d * 32 + g * 4) = o;
}

// ---------------------------------------------------------------------------
// h = relu(agg1 + b1 + x @ W1_root.T); y2 = h @ W2_rel.T; r2 = h @ W2_root.T
// ---------------------------------------------------------------------------
__global__ __launch_bounds__(256) void k_node1(
    const float* __restrict__ x, const float* __restrict__ agg1,
    const float* __restrict__ W1_root, const float* __restrict__ b1,
    const float* __restrict__ W2_rel, const float* __restrict__ W2_root,
    float* __restrict__ y2, float* __restrict__ r2)
{
    int n = blockIdx.x * 256 + threadIdx.x;
    if (n >= NN) return;
    float xr[64];
    const float4* xrow = reinterpret_cast<const float4*>(x + (size_t)n * 64);
#pragma unroll
    for (int i = 0; i < 16; ++i) {
        float4 v = xrow[i];
        xr[4*i+0] = v.x; xr[4*i+1] = v.y; xr[4*i+2] = v.z; xr[4*i+3] = v.w;
    }
    float h[32];
    const float4* arow = reinterpret_cast<const float4*>(agg1 + (size_t)n * 32);
#pragma unroll
    for (int og = 0; og < 8; ++og) {
        float4 v = arow[og];
        h[og*4+0] = v.x; h[og*4+1] = v.y; h[og*4+2] = v.z; h[og*4+3] = v.w;
    }
#pragma unroll
    for (int o = 0; o < 32; ++o) {
        const float* wrow = W1_root + o * 64;
        float ssum = 0.f;
#pragma unroll
        for (int k = 0; k < 64; ++k) ssum += xr[k] * wrow[k];
        float t = h[o] + b1[o] + ssum;
        h[o] = t > 0.f ? t : 0.f;
    }
    float o2[8], o3[8];
#pragma unroll
    for (int j = 0; j < 8; ++j) {
        const float* wr = W2_rel  + j * 32;
        const float* wo = W2_root + j * 32;
        float s0 = 0.f, s1 = 0.f;
#pragma unroll
        for (int c = 0; c < 32; ++c) { s0 += h[c] * wr[c]; s1 += h[c] * wo[c]; }
        o2[j] = s0; o3[j] = s1;
    }
    float4* y2o = reinterpret_cast<float4*>(y2 + (size_t)n * 8);
    float4* r2o = reinterpret_cast<float4*>(r2 + (size_t)n * 8);
    float4 v0, v1;
    v0.x=o2[0]; v0.y=o2[1]; v0.z=o2[2]; v0.w=o2[3]; y2o[0]=v0;
    v1.x=o2[4]; v1.y=o2[5]; v1.z=o2[6]; v1.w=o2[7]; y2o[1]=v1;
    v0.x=o3[0]; v0.y=o3[1]; v0.z=o3[2]; v0.w=o3[3]; r2o[0]=v0;
    v1.x=o3[4]; v1.y=o3[5]; v1.z=o3[6]; v1.w=o3[7]; r2o[1]=v1;
}

// ---------------------------------------------------------------------------
// Reduce pass 2: 2 lanes per dst row (8 features); register accumulation;
// 4-edge unroll with zero-weight tail masking.
// ---------------------------------------------------------------------------
__global__ __launch_bounds__(256) void k_reduce2(
    const int2* __restrict__ rowptr2, const int2* __restrict__ e_sw,
    const float* __restrict__ y2, float* __restrict__ agg2)
{
    int idx = blockIdx.x * 256 + threadIdx.x;
    int d = idx >> 1;
    if (d >= NN) return;
    int g = idx & 1;
    int2 rp = rowptr2[d];
    int beg = rp.x, end = rp.y;
    float a0 = 0.f, a1 = 0.f, a2 = 0.f, a3 = 0.f;
    for (int e = beg; e < end; e += 4) {
        int eB = e + 1, eC = e + 2, eD = e + 3;
        int lim = end - 1;
        int2 pA = e_sw[e];
        int2 pB = e_sw[eB < lim ? eB : lim];
        int2 pC = e_sw[eC < lim ? eC : lim];
        int2 pD = e_sw[eD < lim ? eD : lim];
        float wA = __int_as_float(pA.y);
        float wB = eB < end ? __int_as_float(pB.y) : 0.f;
        float wC = eC < end ? __int_as_float(pC.y) : 0.f;
        float wD = eD < end ? __int_as_float(pD.y) : 0.f;
        float4 vA = *reinterpret_cast<const float4*>(y2 + (size_t)(pA.x & 0x1FFFF) * 8 + g * 4);
        float4 vB = *reinterpret_cast<const float4*>(y2 + (size_t)(pB.x & 0x1FFFF) * 8 + g * 4);
        float4 vC = *reinterpret_cast<const float4*>(y2 + (size_t)(pC.x & 0x1FFFF) * 8 + g * 4);
        float4 vD = *reinterpret_cast<const float4*>(y2 + (size_t)(pD.x & 0x1FFFF) * 8 + g * 4);
        a0 += vA.x * wA + vB.x * wB + vC.x * wC + vD.x * wD;
        a1 += vA.y * wA + vB.y * wB + vC.y * wC + vD.y * wD;
        a2 += vA.z * wA + vB.z * wB + vC.z * wC + vD.z * wD;
        a3 += vA.w * wA + vB.w * wB + vC.w * wC + vD.w * wD;
    }
    float4 o; o.x = a0; o.y = a1; o.z = a2; o.w = a3;
    *reinterpret_cast<float4*>(agg2 + (size_t)d * 8 + g * 4) = o;
}

// ---------------------------------------------------------------------------
// Final: h2 = agg2 + b2 + r2; emb = log_softmax(h2); out = relu([emb,x1]@W_lin.T+b)
// ---------------------------------------------------------------------------
__global__ __launch_bounds__(256) void k_final(
    const float* __restrict__ agg2, const float* __restrict__ r2,
    const float* __restrict__ x1, const float* __restrict__ b2,
    const float* __restrict__ W_lin, const float* __restrict__ b_lin,
    float* __restrict__ outv, float* __restrict__ emb)
{
    int n = blockIdx.x * 256 + threadIdx.x;
    if (n >= NN) return;
    const float4* arow = reinterpret_cast<const float4*>(agg2 + (size_t)n * 8);
    const float4* rrow = reinterpret_cast<const float4*>(r2   + (size_t)n * 8);
    float h2[8];
    {
        float4 a0 = arow[0], a1 = arow[1], r0 = rrow[0], r1 = rrow[1];
        h2[0]=a0.x+r0.x+b2[0]; h2[1]=a0.y+r0.y+b2[1];
        h2[2]=a0.z+r0.z+b2[2]; h2[3]=a0.w+r0.w+b2[3];
        h2[4]=a1.x+r1.x+b2[4]; h2[5]=a1.y+r1.y+b2[5];
        h2[6]=a1.z+r1.z+b2[6]; h2[7]=a1.w+r1.w+b2[7];
    }
    float m = h2[0];
#pragma unroll
    for (int j = 1; j < 8; ++j) m = fmaxf(m, h2[j]);
    float sum = 0.f;
#pragma unroll
    for (int j = 0; j < 8; ++j) sum += __expf(h2[j] - m);
    float lse = __logf(sum);
    float eb[8];
#pragma unroll
    for (int j = 0; j < 8; ++j) eb[j] = h2[j] - m - lse;
    float4* eo = reinterpret_cast<float4*>(emb + (size_t)n * 8);
    float4 v0, v1;
    v0.x=eb[0]; v0.y=eb[1]; v0.z=eb[2]; v0.w=eb[3]; eo[0]=v0;
    v1.x=eb[4]; v1.y=eb[5]; v1.z=eb[6]; v1.w=eb[7]; eo[1]=v1;
    float acc = b_lin[0] + x1[n] * W_lin[8];
#pragma unroll
    for (int j = 0; j < 8; ++j) acc += eb[j] * W_lin[j];
    outv[n] = acc > 0.f ? acc : 0.f;
}

// ---------------------------------------------------------------------------
extern "C" void kernel_launch(void* const* d_in, const int* in_sizes, int n_in,
                              void* d_out, int out_size, void* d_ws, size_t ws_size,
                              hipStream_t stream) {
    const float* x      = (const float*)d_in[0];
    const int*   ei     = (const int*)  d_in[1];
    const float* ew     = (const float*)d_in[2];
    const float* x1     = (const float*)d_in[3];
    const float* W1_rel = (const float*)d_in[4];
    const float* b1     = (const float*)d_in[5];
    const float* W1_root= (const float*)d_in[6];
    const float* W2_rel = (const float*)d_in[7];
    const float* b2     = (const float*)d_in[8];
    const float* W2_root= (const float*)d_in[9];
    const float* W_lin  = (const float*)d_in[10];
    const float* b_lin  = (const float*)d_in[11];

    float* ws    = (float*)d_ws;
    float* y1    = ws;                           // N*32
    float* agg1  = y1   + (size_t)NN * 32;       // N*32
    float* y2    = agg1 + (size_t)NN * 32;       // N*8
    float* r2    = y2   + (size_t)NN * 8;        // N*8
    float* agg2  = r2   + (size_t)NN * 8;        // N*8
    int*   gcursor = (int*)(agg2 + (size_t)NN * 8);     // NB, padded to 1024
    int2*  rowptr2 = (int2*)(gcursor + 1024);           // NN int2
    int2*  e_sw    = rowptr2 + NN;                      // NB*CAP int2 (128B-aligned)

    float* outv = (float*)d_out;             // N   (output 0)
    float* emb  = outv + NN;                 // N*8 (output 1)

    hipMemsetAsync(gcursor, 0, NB * sizeof(int), stream);

    int nbN = (NN + 255) / 256;
    k_bucket<<<NBLK, THR, 0, stream>>>(ei, ew, gcursor, e_sw);
    k_sort<<<NB, 1024, 0, stream>>>(gcursor, e_sw, rowptr2);
    k_transform1<<<nbN, 256, 0, stream>>>(x, W1_rel, y1);
    k_reduce1<<<(NN * 8 + 255) / 256, 256, 0, stream>>>(rowptr2, e_sw, y1, agg1);
    k_node1<<<nbN, 256, 0, stream>>>(x, agg1, W1_root, b1, W2_rel, W2_root, y2, r2);
    k_reduce2<<<(NN * 2 + 255) / 256, 256, 0, stream>>>(rowptr2, e_sw, y2, agg2);
    k_final<<<nbN, 256, 0, stream>>>(agg2, r2, x1, b2, W_lin, b_lin, outv, emb);
}

// Round 12
// 241.769 us; speedup vs baseline: 1.2337x; 1.0238x over previous
//
#include <hip/hip_runtime.h>
#include <hip/hip_bf16.h>

constexpr int NN = 100000;   // nodes
constexpr int NE = 3200000;  // edges
constexpr int BSHIFT = 8;                       // 256 dsts per bucket
constexpr int BSPAN  = 1 << BSHIFT;
constexpr int NB = (NN + BSPAN - 1) >> BSHIFT;  // 391 buckets
constexpr int CAP = 12288;                      // per-bucket slots; CAP/1024=12
constexpr int NBLK = 256;                       // stage-and-burst blocks (512 thr)
constexpr int THR  = 512;
constexpr int CHUNK = NE / NBLK;                // 12500 edges per block (exact)
constexpr int SLOTS = CAP / 1024;               // 12 register-held edges/thread in k_sort

// bf16 helpers (RNE)
__device__ __forceinline__ unsigned int bf16pack(float a, float b) {
    unsigned int ua = __float_as_uint(a);
    unsigned int ub = __float_as_uint(b);
    ua += 0x7FFF + ((ua >> 16) & 1);
    ub += 0x7FFF + ((ub >> 16) & 1);
    return (ua >> 16) | (ub & 0xFFFF0000u);
}
__device__ __forceinline__ float bfl(unsigned int u) { return __uint_as_float(u << 16); }
__device__ __forceinline__ float bfh(unsigned int u) { return __uint_as_float(u & 0xFFFF0000u); }

// ---------------------------------------------------------------------------
// Pass A: stage-and-burst coarse bucket sort by dst>>8 (round-11, unchanged).
// ---------------------------------------------------------------------------
__global__ __launch_bounds__(THR) void k_bucket(
    const int* __restrict__ ei, const float* __restrict__ ew,
    int* __restrict__ gcursor, int2* __restrict__ e_sw)
{
    __shared__ int2 stash[CHUNK];
    __shared__ unsigned short inv16[CHUNK];
    __shared__ int h[NB];
    __shared__ int scan[THR];
    __shared__ int off[NB];
    __shared__ int gbase[NB];
    int tid = threadIdx.x;
    int e0 = blockIdx.x * CHUNK;

    for (int b = tid; b < NB; b += THR) h[b] = 0;
    __syncthreads();
#pragma unroll
    for (int k = 0; k <= CHUNK / THR; ++k) {
        int j = tid + k * THR;
        if (j < CHUNK) {
            int e = e0 + j;
            int d = ei[NE + e];
            int2 v;
            v.x = ((d & (BSPAN - 1)) << 17) | ei[e];
            v.y = __float_as_int(ew[e]);
            stash[j] = v;
            atomicAdd(&h[d >> BSHIFT], 1);
        }
    }
    __syncthreads();
    scan[tid] = (tid < NB) ? h[tid] : 0;
    __syncthreads();
    for (int o = 1; o < THR; o <<= 1) {
        int v = (tid >= o) ? scan[tid - o] : 0;
        __syncthreads();
        scan[tid] += v;
        __syncthreads();
    }
    if (tid < NB) {
        int c = h[tid];
        int r = (c + 15) & ~15;
        gbase[tid] = r ? atomicAdd(&gcursor[tid], r) : 0;
        off[tid] = scan[tid] - c;
    }
    __syncthreads();
    for (int j = tid; j < CHUNK; j += THR) {
        int b = ei[NE + e0 + j] >> BSHIFT;
        int p = atomicAdd(&off[b], 1);
        inv16[p] = (unsigned short)j;
    }
    __syncthreads();
    for (int i = tid; i < CHUNK; i += THR) {
        int lo = 0, hi = NB - 1;
        while (lo < hi) {
            int mid = (lo + hi) >> 1;
            if (scan[mid] > i) hi = mid; else lo = mid + 1;
        }
        int b = lo;
        int rel = i - (scan[b] - h[b]);
        int2 v = stash[inv16[i]];
        e_sw[(size_t)b * CAP + gbase[b] + rel] = v;
    }
    int2 sv; sv.x = -1; sv.y = 0;
    for (int b = tid; b < NB; b += THR) {
        int c = h[b];
        int r = (c + 15) & ~15;
        for (int p = c; p < r; ++p)
            e_sw[(size_t)b * CAP + gbase[b] + p] = sv;
    }
}

// ---------------------------------------------------------------------------
// Pass B: within-bucket counting sort by dl, in place, sentinel-skipping
// (round-10/11, unchanged).
// ---------------------------------------------------------------------------
__global__ __launch_bounds__(1024) void k_sort(
    const int* __restrict__ gcursor, int2* __restrict__ e_sw,
    int2* __restrict__ rowptr2)
{
    __shared__ int hist[BSPAN];
    __shared__ int startp[BSPAN];
    __shared__ int off[BSPAN];
    int b = blockIdx.x, tid = threadIdx.x;
    int cnt = gcursor[b];
    int2* es = e_sw + (size_t)b * CAP;
    if (tid < BSPAN) hist[tid] = 0;
    __syncthreads();
    int2 held[SLOTS];
#pragma unroll
    for (int k = 0; k < SLOTS; ++k) {
        int i = tid + k * 1024;
        held[k].x = -1;
        if (i < cnt) {
            int2 v = es[i];
            held[k] = v;
            if (v.x >= 0) atomicAdd(&hist[v.x >> 17], 1);
        }
    }
    __syncthreads();
    if (tid < BSPAN) startp[tid] = hist[tid];
    __syncthreads();
    for (int o = 1; o < BSPAN; o <<= 1) {
        int v = (tid < BSPAN && tid >= o) ? startp[tid - o] : 0;
        __syncthreads();
        if (tid < BSPAN) startp[tid] += v;
        __syncthreads();
    }
    int d0 = b << BSHIFT;
    if (tid < BSPAN) {
        int beg_rel = startp[tid] - hist[tid];
        off[tid] = beg_rel;
        int d = d0 + tid;
        if (d < NN) {
            int beg = b * CAP + beg_rel;
            int2 rp; rp.x = beg; rp.y = beg + hist[tid];
            rowptr2[d] = rp;
        }
    }
    __syncthreads();
#pragma unroll
    for (int k = 0; k < SLOTS; ++k) {
        int2 v = held[k];
        if (v.x >= 0) {
            int p = atomicAdd(&off[v.x >> 17], 1);
            es[p] = v;
        }
    }
}

// ---------------------------------------------------------------------------
// Fused transform: y1 = bf16(x @ W1_rel.T), r1 = x @ W1_root.T.
// 4 threads per node (one per wave-quarter q=tid>>6); thread computes 16 of
// the 64 combined outputs. q is wave-uniform -> W rows stay scalar loads.
// x row read per thread; 4x reuse within block is L1-served (16KB tile).
// Grid 1563 blocks = 4x the waves of the old 1-thread-per-node kernel.
// ---------------------------------------------------------------------------
__global__ __launch_bounds__(256) void k_xform(
    const float* __restrict__ x, const float* __restrict__ W1_rel,
    const float* __restrict__ W1_root,
    unsigned int* __restrict__ y1u, float* __restrict__ r1)
{
    int tid = threadIdx.x;
    int q = tid >> 6;                        // wave index 0..3 (uniform per wave)
    int n = blockIdx.x * 64 + (tid & 63);
    if (n >= NN) return;
    float xr[64];
    const float4* xrow = reinterpret_cast<const float4*>(x + (size_t)n * 64);
#pragma unroll
    for (int i = 0; i < 16; ++i) {
        float4 v = xrow[i];
        xr[4*i+0] = v.x; xr[4*i+1] = v.y; xr[4*i+2] = v.z; xr[4*i+3] = v.w;
    }
    const float* Wb = (q < 2) ? (W1_rel + q * 16 * 64)
                              : (W1_root + (q - 2) * 16 * 64);
    float acc[16];
#pragma unroll
    for (int o = 0; o < 16; ++o) {
        const float* wrow = Wb + o * 64;
        float s = 0.f;
#pragma unroll
        for (int k = 0; k < 64; ++k) s += xr[k] * wrow[k];
        acc[o] = s;
    }
    if (q < 2) {
        uint4 a, b;
        a.x = bf16pack(acc[0],  acc[1]);  a.y = bf16pack(acc[2],  acc[3]);
        a.z = bf16pack(acc[4],  acc[5]);  a.w = bf16pack(acc[6],  acc[7]);
        b.x = bf16pack(acc[8],  acc[9]);  b.y = bf16pack(acc[10], acc[11]);
        b.z = bf16pack(acc[12], acc[13]); b.w = bf16pack(acc[14], acc[15]);
        unsigned int* dst = y1u + (size_t)n * 16 + q * 8;
        *reinterpret_cast<uint4*>(dst)     = a;
        *reinterpret_cast<uint4*>(dst + 4) = b;
    } else {
        float* dst = r1 + (size_t)n * 32 + (q - 2) * 16;
#pragma unroll
        for (int i = 0; i < 4; ++i) {
            float4 v; v.x = acc[4*i]; v.y = acc[4*i+1]; v.z = acc[4*i+2]; v.w = acc[4*i+3];
            reinterpret_cast<float4*>(dst)[i] = v;
        }
    }
}

// ---------------------------------------------------------------------------
// Reduce pass 1: 8 lanes per dst row; y1 rows are bf16 (64B/row = 1 line per
// gather). Register accumulation; 4-edge unroll with zero-weight tail mask.
// ---------------------------------------------------------------------------
__global__ __launch_bounds__(256) void k_reduce1(
    const int2* __restrict__ rowptr2, const int2* __restrict__ e_sw,
    const unsigned int* __restrict__ y1u, float* __restrict__ agg1)
{
    int idx = blockIdx.x * 256 + threadIdx.x;
    int d = idx >> 3;
    if (d >= NN) return;
    int g = idx & 7;
    int2 rp = rowptr2[d];
    int beg = rp.x, end = rp.y;
    float a0 = 0.f, a1 = 0.f, a2 = 0.f, a3 = 0.f;
    for (int e = beg; e < end; e += 4) {
        int eB = e + 1, eC = e + 2, eD = e + 3;
        int lim = end - 1;
        int2 pA = e_sw[e];
        int2 pB = e_sw[eB < lim ? eB : lim];
        int2 pC = e_sw[eC < lim ? eC : lim];
        int2 pD = e_sw[eD < lim ? eD : lim];
        float wA = __int_as_float(pA.y);
        float wB = eB < end ? __int_as_float(pB.y) : 0.f;
        float wC = eC < end ? __int_as_float(pC.y) : 0.f;
        float wD = eD < end ? __int_as_float(pD.y) : 0.f;
        uint2 qA = *reinterpret_cast<const uint2*>(y1u + (size_t)(pA.x & 0x1FFFF) * 16 + g * 2);
        uint2 qB = *reinterpret_cast<const uint2*>(y1u + (size_t)(pB.x & 0x1FFFF) * 16 + g * 2);
        uint2 qC = *reinterpret_cast<const uint2*>(y1u + (size_t)(pC.x & 0x1FFFF) * 16 + g * 2);
        uint2 qD = *reinterpret_cast<const uint2*>(y1u + (size_t)(pD.x & 0x1FFFF) * 16 + g * 2);
        a0 += bfl(qA.x) * wA + bfl(qB.x) * wB + bfl(qC.x) * wC + bfl(qD.x) * wD;
        a1 += bfh(qA.x) * wA + bfh(qB.x) * wB + bfh(qC.x) * wC + bfh(qD.x) * wD;
        a2 += bfl(qA.y) * wA + bfl(qB.y) * wB + bfl(qC.y) * wC + bfl(qD.y) * wD;
        a3 += bfh(qA.y) * wA + bfh(qB.y) * wB + bfh(qC.y) * wC + bfh(qD.y) * wD;
    }
    float4 o; o.x = a0; o.y = a1; o.z = a2; o.w = a3;
    *reinterpret_cast<float4*>(agg1 + (size_t)d * 32 + g * 4) = o;
}

// ---------------------------------------------------------------------------
// Node pass (light): h = relu(agg1 + r1 + b1); y2 = h@W2_rel.T; r2 = h@W2_root.T
// ---------------------------------------------------------------------------
__global__ __launch_bounds__(256) void k_node1(
    const float* __restrict__ agg1, const float* __restrict__ r1,
    const float* __restrict__ b1,
    const float* __restrict__ W2_rel, const float* __restrict__ W2_root,
    float* __restrict__ y2, float* __restrict__ r2)
{
    int n = blockIdx.x * 256 + threadIdx.x;
    if (n >= NN) return;
    float h[32];
    const float4* arow = reinterpret_cast<const float4*>(agg1 + (size_t)n * 32);
    const float4* rrow = reinterpret_cast<const float4*>(r1   + (size_t)n * 32);
#pragma unroll
    for (int og = 0; og < 8; ++og) {
        float4 a = arow[og], r = rrow[og];
        float t0 = a.x + r.x + b1[og*4+0];
        float t1 = a.y + r.y + b1[og*4+1];
        float t2 = a.z + r.z + b1[og*4+2];
        float t3 = a.w + r.w + b1[og*4+3];
        h[og*4+0] = t0 > 0.f ? t0 : 0.f;
        h[og*4+1] = t1 > 0.f ? t1 : 0.f;
        h[og*4+2] = t2 > 0.f ? t2 : 0.f;
        h[og*4+3] = t3 > 0.f ? t3 : 0.f;
    }
    float o2[8], o3[8];
#pragma unroll
    for (int j = 0; j < 8; ++j) {
        const float* wr = W2_rel  + j * 32;
        const float* wo = W2_root + j * 32;
        float s0 = 0.f, s1 = 0.f;
#pragma unroll
        for (int c = 0; c < 32; ++c) { s0 += h[c] * wr[c]; s1 += h[c] * wo[c]; }
        o2[j] = s0; o3[j] = s1;
    }
    float4* y2o = reinterpret_cast<float4*>(y2 + (size_t)n * 8);
    float4* r2o = reinterpret_cast<float4*>(r2 + (size_t)n * 8);
    float4 v0, v1;
    v0.x=o2[0]; v0.y=o2[1]; v0.z=o2[2]; v0.w=o2[3]; y2o[0]=v0;
    v1.x=o2[4]; v1.y=o2[5]; v1.z=o2[6]; v1.w=o2[7]; y2o[1]=v1;
    v0.x=o3[0]; v0.y=o3[1]; v0.z=o3[2]; v0.w=o3[3]; r2o[0]=v0;
    v1.x=o3[4]; v1.y=o3[5]; v1.z=o3[6]; v1.w=o3[7]; r2o[1]=v1;
}

// ---------------------------------------------------------------------------
// Reduce pass 2: 2 lanes per dst row (8 f32 features); y2 is L2-resident
// (3.2MB), keep f32. 4-edge unroll with zero-weight tail masking.
// ---------------------------------------------------------------------------
__global__ __launch_bounds__(256) void k_reduce2(
    const int2* __restrict__ rowptr2, const int2* __restrict__ e_sw,
    const float* __restrict__ y2, float* __restrict__ agg2)
{
    int idx = blockIdx.x * 256 + threadIdx.x;
    int d = idx >> 1;
    if (d >= NN) return;
    int g = idx & 1;
    int2 rp = rowptr2[d];
    int beg = rp.x, end = rp.y;
    float a0 = 0.f, a1 = 0.f, a2 = 0.f, a3 = 0.f;
    for (int e = beg; e < end; e += 4) {
        int eB = e + 1, eC = e + 2, eD = e + 3;
        int lim = end - 1;
        int2 pA = e_sw[e];
        int2 pB = e_sw[eB < lim ? eB : lim];
        int2 pC = e_sw[eC < lim ? eC : lim];
        int2 pD = e_sw[eD < lim ? eD : lim];
        float wA = __int_as_float(pA.y);
        float wB = eB < end ? __int_as_float(pB.y) : 0.f;
        float wC = eC < end ? __int_as_float(pC.y) : 0.f;
        float wD = eD < end ? __int_as_float(pD.y) : 0.f;
        float4 vA = *reinterpret_cast<const float4*>(y2 + (size_t)(pA.x & 0x1FFFF) * 8 + g * 4);
        float4 vB = *reinterpret_cast<const float4*>(y2 + (size_t)(pB.x & 0x1FFFF) * 8 + g * 4);
        float4 vC = *reinterpret_cast<const float4*>(y2 + (size_t)(pC.x & 0x1FFFF) * 8 + g * 4);
        float4 vD = *reinterpret_cast<const float4*>(y2 + (size_t)(pD.x & 0x1FFFF) * 8 + g * 4);
        a0 += vA.x * wA + vB.x * wB + vC.x * wC + vD.x * wD;
        a1 += vA.y * wA + vB.y * wB + vC.y * wC + vD.y * wD;
        a2 += vA.z * wA + vB.z * wB + vC.z * wC + vD.z * wD;
        a3 += vA.w * wA + vB.w * wB + vC.w * wC + vD.w * wD;
    }
    float4 o; o.x = a0; o.y = a1; o.z = a2; o.w = a3;
    *reinterpret_cast<float4*>(agg2 + (size_t)d * 8 + g * 4) = o;
}

// ---------------------------------------------------------------------------
// Final: h2 = agg2 + b2 + r2; emb = log_softmax(h2); out = relu([emb,x1]@W_lin.T+b)
// ---------------------------------------------------------------------------
__global__ __launch_bounds__(256) void k_final(
    const float* __restrict__ agg2, const float* __restrict__ r2,
    const float* __restrict__ x1, const float* __restrict__ b2,
    const float* __restrict__ W_lin, const float* __restrict__ b_lin,
    float* __restrict__ outv, float* __restrict__ emb)
{
    int n = blockIdx.x * 256 + threadIdx.x;
    if (n >= NN) return;
    const float4* arow = reinterpret_cast<const float4*>(agg2 + (size_t)n * 8);
    const float4* rrow = reinterpret_cast<const float4*>(r2   + (size_t)n * 8);
    float h2[8];
    {
        float4 a0 = arow[0], a1 = arow[1], r0 = rrow[0], r1v = rrow[1];
        h2[0]=a0.x+r0.x+b2[0]; h2[1]=a0.y+r0.y+b2[1];
        h2[2]=a0.z+r0.z+b2[2]; h2[3]=a0.w+r0.w+b2[3];
        h2[4]=a1.x+r1v.x+b2[4]; h2[5]=a1.y+r1v.y+b2[5];
        h2[6]=a1.z+r1v.z+b2[6]; h2[7]=a1.w+r1v.w+b2[7];
    }
    float m = h2[0];
#pragma unroll
    for (int j = 1; j < 8; ++j) m = fmaxf(m, h2[j]);
    float sum = 0.f;
#pragma unroll
    for (int j = 0; j < 8; ++j) sum += __expf(h2[j] - m);
    float lse = __logf(sum);
    float eb[8];
#pragma unroll
    for (int j = 0; j < 8; ++j) eb[j] = h2[j] - m - lse;
    float4* eo = reinterpret_cast<float4*>(emb + (size_t)n * 8);
    float4 v0, v1;
    v0.x=eb[0]; v0.y=eb[1]; v0.z=eb[2]; v0.w=eb[3]; eo[0]=v0;
    v1.x=eb[4]; v1.y=eb[5]; v1.z=eb[6]; v1.w=eb[7]; eo[1]=v1;
    float acc = b_lin[0] + x1[n] * W_lin[8];
#pragma unroll
    for (int j = 0; j < 8; ++j) acc += eb[j] * W_lin[j];
    outv[n] = acc > 0.f ? acc : 0.f;
}

// ---------------------------------------------------------------------------
extern "C" void kernel_launch(void* const* d_in, const int* in_sizes, int n_in,
                              void* d_out, int out_size, void* d_ws, size_t ws_size,
                              hipStream_t stream) {
    const float* x      = (const float*)d_in[0];
    const int*   ei     = (const int*)  d_in[1];
    const float* ew     = (const float*)d_in[2];
    const float* x1     = (const float*)d_in[3];
    const float* W1_rel = (const float*)d_in[4];
    const float* b1     = (const float*)d_in[5];
    const float* W1_root= (const float*)d_in[6];
    const float* W2_rel = (const float*)d_in[7];
    const float* b2     = (const float*)d_in[8];
    const float* W2_root= (const float*)d_in[9];
    const float* W_lin  = (const float*)d_in[10];
    const float* b_lin  = (const float*)d_in[11];

    float* ws    = (float*)d_ws;
    unsigned int* y1u = (unsigned int*)ws;              // N*16 uints (bf16 y1, 6.4MB)
    float* agg2  = (float*)ws;                          // N*8 f32 (3.2MB) — aliases dead y1
    float* r1    = (float*)(y1u + (size_t)NN * 16);     // N*32
    float* agg1  = r1   + (size_t)NN * 32;              // N*32
    float* y2    = agg1 + (size_t)NN * 32;              // N*8
    float* r2    = y2   + (size_t)NN * 8;               // N*8
    int*   gcursor = (int*)(r2 + (size_t)NN * 8);       // NB, padded to 1024
    int2*  rowptr2 = (int2*)(gcursor + 1024);           // NN int2
    int2*  e_sw    = rowptr2 + NN;                      // NB*CAP int2

    float* outv = (float*)d_out;             // N   (output 0)
    float* emb  = outv + NN;                 // N*8 (output 1)

    hipMemsetAsync(gcursor, 0, NB * sizeof(int), stream);

    int nbN = (NN + 255) / 256;
    k_bucket<<<NBLK, THR, 0, stream>>>(ei, ew, gcursor, e_sw);
    k_sort<<<NB, 1024, 0, stream>>>(gcursor, e_sw, rowptr2);
    k_xform<<<(NN + 63) / 64, 256, 0, stream>>>(x, W1_rel, W1_root, y1u, r1);
    k_reduce1<<<(NN * 8 + 255) / 256, 256, 0, stream>>>(rowptr2, e_sw, y1u, agg1);
    k_node1<<<nbN, 256, 0, stream>>>(agg1, r1, b1, W2_rel, W2_root, y2, r2);
    k_reduce2<<<(NN * 2 + 255) / 256, 256, 0, stream>>>(rowptr2, e_sw, y2, agg2);
    k_final<<<nbN, 256, 0, stream>>>(agg2, r2, x1, b2, W_lin, b_lin, outv, emb);
}

// Round 13
// 231.583 us; speedup vs baseline: 1.2880x; 1.0440x over previous
//
#include <hip/hip_runtime.h>
#include <hip/hip_bf16.h>

constexpr int NN = 100000;   // nodes
constexpr int NE = 3200000;  // edges
constexpr int BSHIFT = 8;                       // 256 dsts per bucket
constexpr int BSPAN  = 1 << BSHIFT;
constexpr int NB = (NN + BSPAN - 1) >> BSHIFT;  // 391 buckets
constexpr int CAP = 12288;                      // per-bucket slots; CAP/1024=12
constexpr int NBLK = 256;                       // stage-and-burst blocks (512 thr)
constexpr int THR  = 512;
constexpr int CHUNK = NE / NBLK;                // 12500 edges per block (exact)
constexpr int SLOTS = CAP / 1024;               // 12 register-held edges/thread in k_sort
constexpr int XPAD = 68;                        // LDS row pitch (floats), float4-aligned

// bf16 helpers (RNE)
__device__ __forceinline__ unsigned int bf16pack(float a, float b) {
    unsigned int ua = __float_as_uint(a);
    unsigned int ub = __float_as_uint(b);
    ua += 0x7FFF + ((ua >> 16) & 1);
    ub += 0x7FFF + ((ub >> 16) & 1);
    return (ua >> 16) | (ub & 0xFFFF0000u);
}
__device__ __forceinline__ float bfl(unsigned int u) { return __uint_as_float(u << 16); }
__device__ __forceinline__ float bfh(unsigned int u) { return __uint_as_float(u & 0xFFFF0000u); }

// ---------------------------------------------------------------------------
// Pass A: stage-and-burst coarse bucket sort by dst>>8 (round-11, unchanged).
// ---------------------------------------------------------------------------
__global__ __launch_bounds__(THR) void k_bucket(
    const int* __restrict__ ei, const float* __restrict__ ew,
    int* __restrict__ gcursor, int2* __restrict__ e_sw)
{
    __shared__ int2 stash[CHUNK];
    __shared__ unsigned short inv16[CHUNK];
    __shared__ int h[NB];
    __shared__ int scan[THR];
    __shared__ int off[NB];
    __shared__ int gbase[NB];
    int tid = threadIdx.x;
    int e0 = blockIdx.x * CHUNK;

    for (int b = tid; b < NB; b += THR) h[b] = 0;
    __syncthreads();
#pragma unroll
    for (int k = 0; k <= CHUNK / THR; ++k) {
        int j = tid + k * THR;
        if (j < CHUNK) {
            int e = e0 + j;
            int d = ei[NE + e];
            int2 v;
            v.x = ((d & (BSPAN - 1)) << 17) | ei[e];
            v.y = __float_as_int(ew[e]);
            stash[j] = v;
            atomicAdd(&h[d >> BSHIFT], 1);
        }
    }
    __syncthreads();
    scan[tid] = (tid < NB) ? h[tid] : 0;
    __syncthreads();
    for (int o = 1; o < THR; o <<= 1) {
        int v = (tid >= o) ? scan[tid - o] : 0;
        __syncthreads();
        scan[tid] += v;
        __syncthreads();
    }
    if (tid < NB) {
        int c = h[tid];
        int r = (c + 15) & ~15;
        gbase[tid] = r ? atomicAdd(&gcursor[tid], r) : 0;
        off[tid] = scan[tid] - c;
    }
    __syncthreads();
    for (int j = tid; j < CHUNK; j += THR) {
        int b = ei[NE + e0 + j] >> BSHIFT;
        int p = atomicAdd(&off[b], 1);
        inv16[p] = (unsigned short)j;
    }
    __syncthreads();
    for (int i = tid; i < CHUNK; i += THR) {
        int lo = 0, hi = NB - 1;
        while (lo < hi) {
            int mid = (lo + hi) >> 1;
            if (scan[mid] > i) hi = mid; else lo = mid + 1;
        }
        int b = lo;
        int rel = i - (scan[b] - h[b]);
        int2 v = stash[inv16[i]];
        e_sw[(size_t)b * CAP + gbase[b] + rel] = v;
    }
    int2 sv; sv.x = -1; sv.y = 0;
    for (int b = tid; b < NB; b += THR) {
        int c = h[b];
        int r = (c + 15) & ~15;
        for (int p = c; p < r; ++p)
            e_sw[(size_t)b * CAP + gbase[b] + p] = sv;
    }
}

// ---------------------------------------------------------------------------
// Pass B: within-bucket counting sort by dl, in place, sentinel-skipping
// (unchanged).
// ---------------------------------------------------------------------------
__global__ __launch_bounds__(1024) void k_sort(
    const int* __restrict__ gcursor, int2* __restrict__ e_sw,
    int2* __restrict__ rowptr2)
{
    __shared__ int hist[BSPAN];
    __shared__ int startp[BSPAN];
    __shared__ int off[BSPAN];
    int b = blockIdx.x, tid = threadIdx.x;
    int cnt = gcursor[b];
    int2* es = e_sw + (size_t)b * CAP;
    if (tid < BSPAN) hist[tid] = 0;
    __syncthreads();
    int2 held[SLOTS];
#pragma unroll
    for (int k = 0; k < SLOTS; ++k) {
        int i = tid + k * 1024;
        held[k].x = -1;
        if (i < cnt) {
            int2 v = es[i];
            held[k] = v;
            if (v.x >= 0) atomicAdd(&hist[v.x >> 17], 1);
        }
    }
    __syncthreads();
    if (tid < BSPAN) startp[tid] = hist[tid];
    __syncthreads();
    for (int o = 1; o < BSPAN; o <<= 1) {
        int v = (tid < BSPAN && tid >= o) ? startp[tid - o] : 0;
        __syncthreads();
        if (tid < BSPAN) startp[tid] += v;
        __syncthreads();
    }
    int d0 = b << BSHIFT;
    if (tid < BSPAN) {
        int beg_rel = startp[tid] - hist[tid];
        off[tid] = beg_rel;
        int d = d0 + tid;
        if (d < NN) {
            int beg = b * CAP + beg_rel;
            int2 rp; rp.x = beg; rp.y = beg + hist[tid];
            rowptr2[d] = rp;
        }
    }
    __syncthreads();
#pragma unroll
    for (int k = 0; k < SLOTS; ++k) {
        int2 v = held[k];
        if (v.x >= 0) {
            int p = atomicAdd(&off[v.x >> 17], 1);
            es[p] = v;
        }
    }
}

// ---------------------------------------------------------------------------
// Fused transform v2 (LDS-staged): y1 = bf16(x @ W1_rel.T), r1 = x @ W1_root.T.
// Stage 64 node-rows (16KB) into LDS with COALESCED float4 global loads
// (round-12 lesson: thread-per-row float4 loads have 256B lane stride = 64
// lines per instruction). Compute k-outer from LDS; W via wave-uniform
// s_loads. acc[16] keeps VGPR ~40 -> 8 waves/SIMD.
// ---------------------------------------------------------------------------
__global__ __launch_bounds__(256) void k_xform(
    const float* __restrict__ x, const float* __restrict__ W1_rel,
    const float* __restrict__ W1_root,
    unsigned int* __restrict__ y1u, float* __restrict__ r1)
{
    __shared__ float xt[64 * XPAD];
    int tid = threadIdx.x;
    int n0 = blockIdx.x * 64;
    int nend = NN - n0; if (nend > 64) nend = 64;
    for (int i = tid; i < nend * 16; i += 256) {
        int n = i >> 4, k4 = (i & 15) << 2;
        float4 v = *reinterpret_cast<const float4*>(x + (size_t)(n0 + n) * 64 + k4);
        *reinterpret_cast<float4*>(&xt[n * XPAD + k4]) = v;
    }
    __syncthreads();
    int q = tid >> 6;                        // 0..3, wave-uniform
    int n = tid & 63;
    if (n >= nend) return;
    const float* Wb = (q < 2) ? (W1_rel + q * 16 * 64)
                              : (W1_root + (q - 2) * 16 * 64);
    float acc[16];
#pragma unroll
    for (int o = 0; o < 16; ++o) acc[o] = 0.f;
    const float* xrow = &xt[n * XPAD];
    for (int kt = 0; kt < 16; ++kt) {        // rolled: 1 ds_read_b128 + 16x4 FMA
        float4 xv = *reinterpret_cast<const float4*>(xrow + kt * 4);
#pragma unroll
        for (int o = 0; o < 16; ++o) {
            const float* w = Wb + o * 64 + kt * 4;
            acc[o] += xv.x * w[0] + xv.y * w[1] + xv.z * w[2] + xv.w * w[3];
        }
    }
    int node = n0 + n;
    if (q < 2) {
        uint4 a, b;
        a.x = bf16pack(acc[0],  acc[1]);  a.y = bf16pack(acc[2],  acc[3]);
        a.z = bf16pack(acc[4],  acc[5]);  a.w = bf16pack(acc[6],  acc[7]);
        b.x = bf16pack(acc[8],  acc[9]);  b.y = bf16pack(acc[10], acc[11]);
        b.z = bf16pack(acc[12], acc[13]); b.w = bf16pack(acc[14], acc[15]);
        unsigned int* dst = y1u + (size_t)node * 16 + q * 8;
        *reinterpret_cast<uint4*>(dst)     = a;
        *reinterpret_cast<uint4*>(dst + 4) = b;
    } else {
        float* dst = r1 + (size_t)node * 32 + (q - 2) * 16;
#pragma unroll
        for (int i = 0; i < 4; ++i) {
            float4 v; v.x = acc[4*i]; v.y = acc[4*i+1]; v.z = acc[4*i+2]; v.w = acc[4*i+3];
            reinterpret_cast<float4*>(dst)[i] = v;
        }
    }
}

// ---------------------------------------------------------------------------
// Reduce pass 1: 8 lanes per dst row; y1 rows are bf16 (64B/row). Register
// accumulation; 4-edge unroll with zero-weight tail masking. (unchanged)
// ---------------------------------------------------------------------------
__global__ __launch_bounds__(256) void k_reduce1(
    const int2* __restrict__ rowptr2, const int2* __restrict__ e_sw,
    const unsigned int* __restrict__ y1u, float* __restrict__ agg1)
{
    int idx = blockIdx.x * 256 + threadIdx.x;
    int d = idx >> 3;
    if (d >= NN) return;
    int g = idx & 7;
    int2 rp = rowptr2[d];
    int beg = rp.x, end = rp.y;
    float a0 = 0.f, a1 = 0.f, a2 = 0.f, a3 = 0.f;
    for (int e = beg; e < end; e += 4) {
        int eB = e + 1, eC = e + 2, eD = e + 3;
        int lim = end - 1;
        int2 pA = e_sw[e];
        int2 pB = e_sw[eB < lim ? eB : lim];
        int2 pC = e_sw[eC < lim ? eC : lim];
        int2 pD = e_sw[eD < lim ? eD : lim];
        float wA = __int_as_float(pA.y);
        float wB = eB < end ? __int_as_float(pB.y) : 0.f;
        float wC = eC < end ? __int_as_float(pC.y) : 0.f;
        float wD = eD < end ? __int_as_float(pD.y) : 0.f;
        uint2 qA = *reinterpret_cast<const uint2*>(y1u + (size_t)(pA.x & 0x1FFFF) * 16 + g * 2);
        uint2 qB = *reinterpret_cast<const uint2*>(y1u + (size_t)(pB.x & 0x1FFFF) * 16 + g * 2);
        uint2 qC = *reinterpret_cast<const uint2*>(y1u + (size_t)(pC.x & 0x1FFFF) * 16 + g * 2);
        uint2 qD = *reinterpret_cast<const uint2*>(y1u + (size_t)(pD.x & 0x1FFFF) * 16 + g * 2);
        a0 += bfl(qA.x) * wA + bfl(qB.x) * wB + bfl(qC.x) * wC + bfl(qD.x) * wD;
        a1 += bfh(qA.x) * wA + bfh(qB.x) * wB + bfh(qC.x) * wC + bfh(qD.x) * wD;
        a2 += bfl(qA.y) * wA + bfl(qB.y) * wB + bfl(qC.y) * wC + bfl(qD.y) * wD;
        a3 += bfh(qA.y) * wA + bfh(qB.y) * wB + bfh(qC.y) * wC + bfh(qD.y) * wD;
    }
    float4 o; o.x = a0; o.y = a1; o.z = a2; o.w = a3;
    *reinterpret_cast<float4*>(agg1 + (size_t)d * 32 + g * 4) = o;
}

// ---------------------------------------------------------------------------
// Node pass (light): h = relu(agg1 + r1 + b1); y2 = h@W2_rel.T; r2 = h@W2_root.T
// (unchanged)
// ---------------------------------------------------------------------------
__global__ __launch_bounds__(256) void k_node1(
    const float* __restrict__ agg1, const float* __restrict__ r1,
    const float* __restrict__ b1,
    const float* __restrict__ W2_rel, const float* __restrict__ W2_root,
    float* __restrict__ y2, float* __restrict__ r2)
{
    int n = blockIdx.x * 256 + threadIdx.x;
    if (n >= NN) return;
    float h[32];
    const float4* arow = reinterpret_cast<const float4*>(agg1 + (size_t)n * 32);
    const float4* rrow = reinterpret_cast<const float4*>(r1   + (size_t)n * 32);
#pragma unroll
    for (int og = 0; og < 8; ++og) {
        float4 a = arow[og], r = rrow[og];
        float t0 = a.x + r.x + b1[og*4+0];
        float t1 = a.y + r.y + b1[og*4+1];
        float t2 = a.z + r.z + b1[og*4+2];
        float t3 = a.w + r.w + b1[og*4+3];
        h[og*4+0] = t0 > 0.f ? t0 : 0.f;
        h[og*4+1] = t1 > 0.f ? t1 : 0.f;
        h[og*4+2] = t2 > 0.f ? t2 : 0.f;
        h[og*4+3] = t3 > 0.f ? t3 : 0.f;
    }
    float o2[8], o3[8];
#pragma unroll
    for (int j = 0; j < 8; ++j) {
        const float* wr = W2_rel  + j * 32;
        const float* wo = W2_root + j * 32;
        float s0 = 0.f, s1 = 0.f;
#pragma unroll
        for (int c = 0; c < 32; ++c) { s0 += h[c] * wr[c]; s1 += h[c] * wo[c]; }
        o2[j] = s0; o3[j] = s1;
    }
    float4* y2o = reinterpret_cast<float4*>(y2 + (size_t)n * 8);
    float4* r2o = reinterpret_cast<float4*>(r2 + (size_t)n * 8);
    float4 v0, v1;
    v0.x=o2[0]; v0.y=o2[1]; v0.z=o2[2]; v0.w=o2[3]; y2o[0]=v0;
    v1.x=o2[4]; v1.y=o2[5]; v1.z=o2[6]; v1.w=o2[7]; y2o[1]=v1;
    v0.x=o3[0]; v0.y=o3[1]; v0.z=o3[2]; v0.w=o3[3]; r2o[0]=v0;
    v1.x=o3[4]; v1.y=o3[5]; v1.z=o3[6]; v1.w=o3[7]; r2o[1]=v1;
}

// ---------------------------------------------------------------------------
// Reduce pass 2: 2 lanes per dst row (8 f32 features). (unchanged)
// ---------------------------------------------------------------------------
__global__ __launch_bounds__(256) void k_reduce2(
    const int2* __restrict__ rowptr2, const int2* __restrict__ e_sw,
    const float* __restrict__ y2, float* __restrict__ agg2)
{
    int idx = blockIdx.x * 256 + threadIdx.x;
    int d = idx >> 1;
    if (d >= NN) return;
    int g = idx & 1;
    int2 rp = rowptr2[d];
    int beg = rp.x, end = rp.y;
    float a0 = 0.f, a1 = 0.f, a2 = 0.f, a3 = 0.f;
    for (int e = beg; e < end; e += 4) {
        int eB = e + 1, eC = e + 2, eD = e + 3;
        int lim = end - 1;
        int2 pA = e_sw[e];
        int2 pB = e_sw[eB < lim ? eB : lim];
        int2 pC = e_sw[eC < lim ? eC : lim];
        int2 pD = e_sw[eD < lim ? eD : lim];
        float wA = __int_as_float(pA.y);
        float wB = eB < end ? __int_as_float(pB.y) : 0.f;
        float wC = eC < end ? __int_as_float(pC.y) : 0.f;
        float wD = eD < end ? __int_as_float(pD.y) : 0.f;
        float4 vA = *reinterpret_cast<const float4*>(y2 + (size_t)(pA.x & 0x1FFFF) * 8 + g * 4);
        float4 vB = *reinterpret_cast<const float4*>(y2 + (size_t)(pB.x & 0x1FFFF) * 8 + g * 4);
        float4 vC = *reinterpret_cast<const float4*>(y2 + (size_t)(pC.x & 0x1FFFF) * 8 + g * 4);
        float4 vD = *reinterpret_cast<const float4*>(y2 + (size_t)(pD.x & 0x1FFFF) * 8 + g * 4);
        a0 += vA.x * wA + vB.x * wB + vC.x * wC + vD.x * wD;
        a1 += vA.y * wA + vB.y * wB + vC.y * wC + vD.y * wD;
        a2 += vA.z * wA + vB.z * wB + vC.z * wC + vD.z * wD;
        a3 += vA.w * wA + vB.w * wB + vC.w * wC + vD.w * wD;
    }
    float4 o; o.x = a0; o.y = a1; o.z = a2; o.w = a3;
    *reinterpret_cast<float4*>(agg2 + (size_t)d * 8 + g * 4) = o;
}

// ---------------------------------------------------------------------------
// Final: h2 = agg2 + b2 + r2; emb = log_softmax(h2); out = relu([emb,x1]@W_lin.T+b)
// (unchanged)
// ---------------------------------------------------------------------------
__global__ __launch_bounds__(256) void k_final(
    const float* __restrict__ agg2, const float* __restrict__ r2,
    const float* __restrict__ x1, const float* __restrict__ b2,
    const float* __restrict__ W_lin, const float* __restrict__ b_lin,
    float* __restrict__ outv, float* __restrict__ emb)
{
    int n = blockIdx.x * 256 + threadIdx.x;
    if (n >= NN) return;
    const float4* arow = reinterpret_cast<const float4*>(agg2 + (size_t)n * 8);
    const float4* rrow = reinterpret_cast<const float4*>(r2   + (size_t)n * 8);
    float h2[8];
    {
        float4 a0 = arow[0], a1 = arow[1], r0 = rrow[0], r1v = rrow[1];
        h2[0]=a0.x+r0.x+b2[0]; h2[1]=a0.y+r0.y+b2[1];
        h2[2]=a0.z+r0.z+b2[2]; h2[3]=a0.w+r0.w+b2[3];
        h2[4]=a1.x+r1v.x+b2[4]; h2[5]=a1.y+r1v.y+b2[5];
        h2[6]=a1.z+r1v.z+b2[6]; h2[7]=a1.w+r1v.w+b2[7];
    }
    float m = h2[0];
#pragma unroll
    for (int j = 1; j < 8; ++j) m = fmaxf(m, h2[j]);
    float sum = 0.f;
#pragma unroll
    for (int j = 0; j < 8; ++j) sum += __expf(h2[j] - m);
    float lse = __logf(sum);
    float eb[8];
#pragma unroll
    for (int j = 0; j < 8; ++j) eb[j] = h2[j] - m - lse;
    float4* eo = reinterpret_cast<float4*>(emb + (size_t)n * 8);
    float4 v0, v1;
    v0.x=eb[0]; v0.y=eb[1]; v0.z=eb[2]; v0.w=eb[3]; eo[0]=v0;
    v1.x=eb[4]; v1.y=eb[5]; v1.z=eb[6]; v1.w=eb[7]; eo[1]=v1;
    float acc = b_lin[0] + x1[n] * W_lin[8];
#pragma unroll
    for (int j = 0; j < 8; ++j) acc += eb[j] * W_lin[j];
    outv[n] = acc > 0.f ? acc : 0.f;
}

// ---------------------------------------------------------------------------
extern "C" void kernel_launch(void* const* d_in, const int* in_sizes, int n_in,
                              void* d_out, int out_size, void* d_ws, size_t ws_size,
                              hipStream_t stream) {
    const float* x      = (const float*)d_in[0];
    const int*   ei     = (const int*)  d_in[1];
    const float* ew     = (const float*)d_in[2];
    const float* x1     = (const float*)d_in[3];
    const float* W1_rel = (const float*)d_in[4];
    const float* b1     = (const float*)d_in[5];
    const float* W1_root= (const float*)d_in[6];
    const float* W2_rel = (const float*)d_in[7];
    const float* b2     = (const float*)d_in[8];
    const float* W2_root= (const float*)d_in[9];
    const float* W_lin  = (const float*)d_in[10];
    const float* b_lin  = (const float*)d_in[11];

    float* ws    = (float*)d_ws;
    unsigned int* y1u = (unsigned int*)ws;              // N*16 uints (bf16 y1, 6.4MB)
    float* agg2  = (float*)ws;                          // N*8 f32 — aliases dead y1
    float* r1    = (float*)(y1u + (size_t)NN * 16);     // N*32
    float* agg1  = r1   + (size_t)NN * 32;              // N*32
    float* y2    = agg1 + (size_t)NN * 32;              // N*8
    float* r2    = y2   + (size_t)NN * 8;               // N*8
    int*   gcursor = (int*)(r2 + (size_t)NN * 8);       // NB, padded to 1024
    int2*  rowptr2 = (int2*)(gcursor + 1024);           // NN int2
    int2*  e_sw    = rowptr2 + NN;                      // NB*CAP int2

    float* outv = (float*)d_out;             // N   (output 0)
    float* emb  = outv + NN;                 // N*8 (output 1)

    hipMemsetAsync(gcursor, 0, NB * sizeof(int), stream);

    int nbN = (NN + 255) / 256;
    k_bucket<<<NBLK, THR, 0, stream>>>(ei, ew, gcursor, e_sw);
    k_sort<<<NB, 1024, 0, stream>>>(gcursor, e_sw, rowptr2);
    k_xform<<<(NN + 63) / 64, 256, 0, stream>>>(x, W1_rel, W1_root, y1u, r1);
    k_reduce1<<<(NN * 8 + 255) / 256, 256, 0, stream>>>(rowptr2, e_sw, y1u, agg1);
    k_node1<<<nbN, 256, 0, stream>>>(agg1, r1, b1, W2_rel, W2_root, y2, r2);
    k_reduce2<<<(NN * 2 + 255) / 256, 256, 0, stream>>>(rowptr2, e_sw, y2, agg2);
    k_final<<<nbN, 256, 0, stream>>>(agg2, r2, x1, b2, W_lin, b_lin, outv, emb);
}

// Round 14
// 200.856 us; speedup vs baseline: 1.4850x; 1.1530x over previous
//
#include <hip/hip_runtime.h>
#include <hip/hip_bf16.h>

constexpr int NN = 100000;   // nodes
constexpr int NE = 3200000;  // edges
constexpr int BSHIFT = 8;                       // 256 dsts per bucket
constexpr int BSPAN  = 1 << BSHIFT;
constexpr int NB = (NN + BSPAN - 1) >> BSHIFT;  // 391 buckets
constexpr int CAP = 12288;                      // per-bucket slots; CAP/1024=12
constexpr int NBLK = 256;                       // stage-and-burst blocks (512 thr)
constexpr int THR  = 512;
constexpr int CHUNK = NE / NBLK;                // 12500 edges per block (exact)
constexpr int SLOTS = CAP / 1024;               // 12 register-held edges/thread in k_sort
constexpr int XPAD = 68;                        // LDS row pitch (floats), float4-aligned

// bf16 helpers (RNE)
__device__ __forceinline__ unsigned int bf16pack(float a, float b) {
    unsigned int ua = __float_as_uint(a);
    unsigned int ub = __float_as_uint(b);
    ua += 0x7FFF + ((ua >> 16) & 1);
    ub += 0x7FFF + ((ub >> 16) & 1);
    return (ua >> 16) | (ub & 0xFFFF0000u);
}
__device__ __forceinline__ float bfl(unsigned int u) { return __uint_as_float(u << 16); }
__device__ __forceinline__ float bfh(unsigned int u) { return __uint_as_float(u & 0xFFFF0000u); }

// ---------------------------------------------------------------------------
// Pass A: stage-and-burst coarse bucket sort by dst>>8 (round-11, unchanged).
// ---------------------------------------------------------------------------
__global__ __launch_bounds__(THR) void k_bucket(
    const int* __restrict__ ei, const float* __restrict__ ew,
    int* __restrict__ gcursor, int2* __restrict__ e_sw)
{
    __shared__ int2 stash[CHUNK];
    __shared__ unsigned short inv16[CHUNK];
    __shared__ int h[NB];
    __shared__ int scan[THR];
    __shared__ int off[NB];
    __shared__ int gbase[NB];
    int tid = threadIdx.x;
    int e0 = blockIdx.x * CHUNK;

    for (int b = tid; b < NB; b += THR) h[b] = 0;
    __syncthreads();
#pragma unroll
    for (int k = 0; k <= CHUNK / THR; ++k) {
        int j = tid + k * THR;
        if (j < CHUNK) {
            int e = e0 + j;
            int d = ei[NE + e];
            int2 v;
            v.x = ((d & (BSPAN - 1)) << 17) | ei[e];
            v.y = __float_as_int(ew[e]);
            stash[j] = v;
            atomicAdd(&h[d >> BSHIFT], 1);
        }
    }
    __syncthreads();
    scan[tid] = (tid < NB) ? h[tid] : 0;
    __syncthreads();
    for (int o = 1; o < THR; o <<= 1) {
        int v = (tid >= o) ? scan[tid - o] : 0;
        __syncthreads();
        scan[tid] += v;
        __syncthreads();
    }
    if (tid < NB) {
        int c = h[tid];
        int r = (c + 15) & ~15;
        gbase[tid] = r ? atomicAdd(&gcursor[tid], r) : 0;
        off[tid] = scan[tid] - c;
    }
    __syncthreads();
    for (int j = tid; j < CHUNK; j += THR) {
        int b = ei[NE + e0 + j] >> BSHIFT;
        int p = atomicAdd(&off[b], 1);
        inv16[p] = (unsigned short)j;
    }
    __syncthreads();
    for (int i = tid; i < CHUNK; i += THR) {
        int lo = 0, hi = NB - 1;
        while (lo < hi) {
            int mid = (lo + hi) >> 1;
            if (scan[mid] > i) hi = mid; else lo = mid + 1;
        }
        int b = lo;
        int rel = i - (scan[b] - h[b]);
        int2 v = stash[inv16[i]];
        e_sw[(size_t)b * CAP + gbase[b] + rel] = v;
    }
    int2 sv; sv.x = -1; sv.y = 0;
    for (int b = tid; b < NB; b += THR) {
        int c = h[b];
        int r = (c + 15) & ~15;
        for (int p = c; p < r; ++p)
            e_sw[(size_t)b * CAP + gbase[b] + p] = sv;
    }
}

// ---------------------------------------------------------------------------
// Pass B: within-bucket counting sort by dl, in place, sentinel-skipping
// (unchanged).
// ---------------------------------------------------------------------------
__global__ __launch_bounds__(1024) void k_sort(
    const int* __restrict__ gcursor, int2* __restrict__ e_sw,
    int2* __restrict__ rowptr2)
{
    __shared__ int hist[BSPAN];
    __shared__ int startp[BSPAN];
    __shared__ int off[BSPAN];
    int b = blockIdx.x, tid = threadIdx.x;
    int cnt = gcursor[b];
    int2* es = e_sw + (size_t)b * CAP;
    if (tid < BSPAN) hist[tid] = 0;
    __syncthreads();
    int2 held[SLOTS];
#pragma unroll
    for (int k = 0; k < SLOTS; ++k) {
        int i = tid + k * 1024;
        held[k].x = -1;
        if (i < cnt) {
            int2 v = es[i];
            held[k] = v;
            if (v.x >= 0) atomicAdd(&hist[v.x >> 17], 1);
        }
    }
    __syncthreads();
    if (tid < BSPAN) startp[tid] = hist[tid];
    __syncthreads();
    for (int o = 1; o < BSPAN; o <<= 1) {
        int v = (tid < BSPAN && tid >= o) ? startp[tid - o] : 0;
        __syncthreads();
        if (tid < BSPAN) startp[tid] += v;
        __syncthreads();
    }
    int d0 = b << BSHIFT;
    if (tid < BSPAN) {
        int beg_rel = startp[tid] - hist[tid];
        off[tid] = beg_rel;
        int d = d0 + tid;
        if (d < NN) {
            int beg = b * CAP + beg_rel;
            int2 rp; rp.x = beg; rp.y = beg + hist[tid];
            rowptr2[d] = rp;
        }
    }
    __syncthreads();
#pragma unroll
    for (int k = 0; k < SLOTS; ++k) {
        int2 v = held[k];
        if (v.x >= 0) {
            int p = atomicAdd(&off[v.x >> 17], 1);
            es[p] = v;
        }
    }
}

// ---------------------------------------------------------------------------
// Fused transform v4: y1 = bf16(x @ W1_rel.T), r1 = x @ W1_root.T.
// Round-13 lesson: the 68us was the per-kt W-load latency chain (global
// vector loads, ~150-300cy each step, compiler can't prove q uniform ->
// no s_loads). Fix: stage W (combined 64x64, 16KB) in LDS; W reads become
// wave-uniform LDS addresses -> hardware broadcast, conflict-free, short
// latency. kt unrolled 4x -> 4 independent read batches in flight.
// ---------------------------------------------------------------------------
__global__ __launch_bounds__(256) void k_xform(
    const float* __restrict__ x, const float* __restrict__ W1_rel,
    const float* __restrict__ W1_root,
    unsigned int* __restrict__ y1u, float* __restrict__ r1)
{
    __shared__ float xt[64 * XPAD];   // 17408 B
    __shared__ float wt[64 * 64];     // 16384 B: rows 0-31 W1_rel, 32-63 W1_root
    int tid = threadIdx.x;
    int n0 = blockIdx.x * 64;
    int nend = NN - n0; if (nend > 64) nend = 64;
    // stage W coalesced (512 float4 per half)
    for (int i = tid; i < 512; i += 256) {
        float4 a = reinterpret_cast<const float4*>(W1_rel)[i];
        float4 b = reinterpret_cast<const float4*>(W1_root)[i];
        reinterpret_cast<float4*>(wt)[i]       = a;
        reinterpret_cast<float4*>(wt)[i + 512] = b;
    }
    // stage x rows coalesced
    for (int i = tid; i < nend * 16; i += 256) {
        int n = i >> 4, k4 = (i & 15) << 2;
        float4 v = *reinterpret_cast<const float4*>(x + (size_t)(n0 + n) * 64 + k4);
        *reinterpret_cast<float4*>(&xt[n * XPAD + k4]) = v;
    }
    __syncthreads();
    int q = tid >> 6;                        // 0..3, wave-uniform
    int n = tid & 63;
    if (n >= nend) return;
    const float* Wb = &wt[q * 16 * 64];      // wave-uniform LDS base
    float acc[16];
#pragma unroll
    for (int o = 0; o < 16; ++o) acc[o] = 0.f;
    const float* xrow = &xt[n * XPAD];
#pragma unroll 4
    for (int kt = 0; kt < 16; ++kt) {
        float4 xv = *reinterpret_cast<const float4*>(xrow + kt * 4);
#pragma unroll
        for (int o = 0; o < 16; ++o) {
            const float* w = Wb + o * 64 + kt * 4;   // uniform -> LDS broadcast
            acc[o] += xv.x * w[0] + xv.y * w[1] + xv.z * w[2] + xv.w * w[3];
        }
    }
    int node = n0 + n;
    if (q < 2) {
        uint4 a, b;
        a.x = bf16pack(acc[0],  acc[1]);  a.y = bf16pack(acc[2],  acc[3]);
        a.z = bf16pack(acc[4],  acc[5]);  a.w = bf16pack(acc[6],  acc[7]);
        b.x = bf16pack(acc[8],  acc[9]);  b.y = bf16pack(acc[10], acc[11]);
        b.z = bf16pack(acc[12], acc[13]); b.w = bf16pack(acc[14], acc[15]);
        unsigned int* dst = y1u + (size_t)node * 16 + q * 8;
        *reinterpret_cast<uint4*>(dst)     = a;
        *reinterpret_cast<uint4*>(dst + 4) = b;
    } else {
        float* dst = r1 + (size_t)node * 32 + (q - 2) * 16;
#pragma unroll
        for (int i = 0; i < 4; ++i) {
            float4 v; v.x = acc[4*i]; v.y = acc[4*i+1]; v.z = acc[4*i+2]; v.w = acc[4*i+3];
            reinterpret_cast<float4*>(dst)[i] = v;
        }
    }
}

// ---------------------------------------------------------------------------
// Reduce pass 1: 8 lanes per dst row; y1 rows are bf16 (64B/row). Register
// accumulation; 4-edge unroll with zero-weight tail masking. (unchanged)
// ---------------------------------------------------------------------------
__global__ __launch_bounds__(256) void k_reduce1(
    const int2* __restrict__ rowptr2, const int2* __restrict__ e_sw,
    const unsigned int* __restrict__ y1u, float* __restrict__ agg1)
{
    int idx = blockIdx.x * 256 + threadIdx.x;
    int d = idx >> 3;
    if (d >= NN) return;
    int g = idx & 7;
    int2 rp = rowptr2[d];
    int beg = rp.x, end = rp.y;
    float a0 = 0.f, a1 = 0.f, a2 = 0.f, a3 = 0.f;
    for (int e = beg; e < end; e += 4) {
        int eB = e + 1, eC = e + 2, eD = e + 3;
        int lim = end - 1;
        int2 pA = e_sw[e];
        int2 pB = e_sw[eB < lim ? eB : lim];
        int2 pC = e_sw[eC < lim ? eC : lim];
        int2 pD = e_sw[eD < lim ? eD : lim];
        float wA = __int_as_float(pA.y);
        float wB = eB < end ? __int_as_float(pB.y) : 0.f;
        float wC = eC < end ? __int_as_float(pC.y) : 0.f;
        float wD = eD < end ? __int_as_float(pD.y) : 0.f;
        uint2 qA = *reinterpret_cast<const uint2*>(y1u + (size_t)(pA.x & 0x1FFFF) * 16 + g * 2);
        uint2 qB = *reinterpret_cast<const uint2*>(y1u + (size_t)(pB.x & 0x1FFFF) * 16 + g * 2);
        uint2 qC = *reinterpret_cast<const uint2*>(y1u + (size_t)(pC.x & 0x1FFFF) * 16 + g * 2);
        uint2 qD = *reinterpret_cast<const uint2*>(y1u + (size_t)(pD.x & 0x1FFFF) * 16 + g * 2);
        a0 += bfl(qA.x) * wA + bfl(qB.x) * wB + bfl(qC.x) * wC + bfl(qD.x) * wD;
        a1 += bfh(qA.x) * wA + bfh(qB.x) * wB + bfh(qC.x) * wC + bfh(qD.x) * wD;
        a2 += bfl(qA.y) * wA + bfl(qB.y) * wB + bfl(qC.y) * wC + bfl(qD.y) * wD;
        a3 += bfh(qA.y) * wA + bfh(qB.y) * wB + bfh(qC.y) * wC + bfh(qD.y) * wD;
    }
    float4 o; o.x = a0; o.y = a1; o.z = a2; o.w = a3;
    *reinterpret_cast<float4*>(agg1 + (size_t)d * 32 + g * 4) = o;
}

// ---------------------------------------------------------------------------
// Node pass (light): h = relu(agg1 + r1 + b1); y2 = h@W2_rel.T; r2 = h@W2_root.T
// (unchanged)
// ---------------------------------------------------------------------------
__global__ __launch_bounds__(256) void k_node1(
    const float* __restrict__ agg1, const float* __restrict__ r1,
    const float* __restrict__ b1,
    const float* __restrict__ W2_rel, const float* __restrict__ W2_root,
    float* __restrict__ y2, float* __restrict__ r2)
{
    int n = blockIdx.x * 256 + threadIdx.x;
    if (n >= NN) return;
    float h[32];
    const float4* arow = reinterpret_cast<const float4*>(agg1 + (size_t)n * 32);
    const float4* rrow = reinterpret_cast<const float4*>(r1   + (size_t)n * 32);
#pragma unroll
    for (int og = 0; og < 8; ++og) {
        float4 a = arow[og], r = rrow[og];
        float t0 = a.x + r.x + b1[og*4+0];
        float t1 = a.y + r.y + b1[og*4+1];
        float t2 = a.z + r.z + b1[og*4+2];
        float t3 = a.w + r.w + b1[og*4+3];
        h[og*4+0] = t0 > 0.f ? t0 : 0.f;
        h[og*4+1] = t1 > 0.f ? t1 : 0.f;
        h[og*4+2] = t2 > 0.f ? t2 : 0.f;
        h[og*4+3] = t3 > 0.f ? t3 : 0.f;
    }
    float o2[8], o3[8];
#pragma unroll
    for (int j = 0; j < 8; ++j) {
        const float* wr = W2_rel  + j * 32;
        const float* wo = W2_root + j * 32;
        float s0 = 0.f, s1 = 0.f;
#pragma unroll
        for (int c = 0; c < 32; ++c) { s0 += h[c] * wr[c]; s1 += h[c] * wo[c]; }
        o2[j] = s0; o3[j] = s1;
    }
    float4* y2o = reinterpret_cast<float4*>(y2 + (size_t)n * 8);
    float4* r2o = reinterpret_cast<float4*>(r2 + (size_t)n * 8);
    float4 v0, v1;
    v0.x=o2[0]; v0.y=o2[1]; v0.z=o2[2]; v0.w=o2[3]; y2o[0]=v0;
    v1.x=o2[4]; v1.y=o2[5]; v1.z=o2[6]; v1.w=o2[7]; y2o[1]=v1;
    v0.x=o3[0]; v0.y=o3[1]; v0.z=o3[2]; v0.w=o3[3]; r2o[0]=v0;
    v1.x=o3[4]; v1.y=o3[5]; v1.z=o3[6]; v1.w=o3[7]; r2o[1]=v1;
}

// ---------------------------------------------------------------------------
// Reduce pass 2: 2 lanes per dst row (8 f32 features). (unchanged)
// ---------------------------------------------------------------------------
__global__ __launch_bounds__(256) void k_reduce2(
    const int2* __restrict__ rowptr2, const int2* __restrict__ e_sw,
    const float* __restrict__ y2, float* __restrict__ agg2)
{
    int idx = blockIdx.x * 256 + threadIdx.x;
    int d = idx >> 1;
    if (d >= NN) return;
    int g = idx & 1;
    int2 rp = rowptr2[d];
    int beg = rp.x, end = rp.y;
    float a0 = 0.f, a1 = 0.f, a2 = 0.f, a3 = 0.f;
    for (int e = beg; e < end; e += 4) {
        int eB = e + 1, eC = e + 2, eD = e + 3;
        int lim = end - 1;
        int2 pA = e_sw[e];
        int2 pB = e_sw[eB < lim ? eB : lim];
        int2 pC = e_sw[eC < lim ? eC : lim];
        int2 pD = e_sw[eD < lim ? eD : lim];
        float wA = __int_as_float(pA.y);
        float wB = eB < end ? __int_as_float(pB.y) : 0.f;
        float wC = eC < end ? __int_as_float(pC.y) : 0.f;
        float wD = eD < end ? __int_as_float(pD.y) : 0.f;
        float4 vA = *reinterpret_cast<const float4*>(y2 + (size_t)(pA.x & 0x1FFFF) * 8 + g * 4);
        float4 vB = *reinterpret_cast<const float4*>(y2 + (size_t)(pB.x & 0x1FFFF) * 8 + g * 4);
        float4 vC = *reinterpret_cast<const float4*>(y2 + (size_t)(pC.x & 0x1FFFF) * 8 + g * 4);
        float4 vD = *reinterpret_cast<const float4*>(y2 + (size_t)(pD.x & 0x1FFFF) * 8 + g * 4);
        a0 += vA.x * wA + vB.x * wB + vC.x * wC + vD.x * wD;
        a1 += vA.y * wA + vB.y * wB + vC.y * wC + vD.y * wD;
        a2 += vA.z * wA + vB.z * wB + vC.z * wC + vD.z * wD;
        a3 += vA.w * wA + vB.w * wB + vC.w * wC + vD.w * wD;
    }
    float4 o; o.x = a0; o.y = a1; o.z = a2; o.w = a3;
    *reinterpret_cast<float4*>(agg2 + (size_t)d * 8 + g * 4) = o;
}

// ---------------------------------------------------------------------------
// Final: h2 = agg2 + b2 + r2; emb = log_softmax(h2); out = relu([emb,x1]@W_lin.T+b)
// (unchanged)
// ---------------------------------------------------------------------------
__global__ __launch_bounds__(256) void k_final(
    const float* __restrict__ agg2, const float* __restrict__ r2,
    const float* __restrict__ x1, const float* __restrict__ b2,
    const float* __restrict__ W_lin, const float* __restrict__ b_lin,
    float* __restrict__ outv, float* __restrict__ emb)
{
    int n = blockIdx.x * 256 + threadIdx.x;
    if (n >= NN) return;
    const float4* arow = reinterpret_cast<const float4*>(agg2 + (size_t)n * 8);
    const float4* rrow = reinterpret_cast<const float4*>(r2   + (size_t)n * 8);
    float h2[8];
    {
        float4 a0 = arow[0], a1 = arow[1], r0 = rrow[0], r1v = rrow[1];
        h2[0]=a0.x+r0.x+b2[0]; h2[1]=a0.y+r0.y+b2[1];
        h2[2]=a0.z+r0.z+b2[2]; h2[3]=a0.w+r0.w+b2[3];
        h2[4]=a1.x+r1v.x+b2[4]; h2[5]=a1.y+r1v.y+b2[5];
        h2[6]=a1.z+r1v.z+b2[6]; h2[7]=a1.w+r1v.w+b2[7];
    }
    float m = h2[0];
#pragma unroll
    for (int j = 1; j < 8; ++j) m = fmaxf(m, h2[j]);
    float sum = 0.f;
#pragma unroll
    for (int j = 0; j < 8; ++j) sum += __expf(h2[j] - m);
    float lse = __logf(sum);
    float eb[8];
#pragma unroll
    for (int j = 0; j < 8; ++j) eb[j] = h2[j] - m - lse;
    float4* eo = reinterpret_cast<float4*>(emb + (size_t)n * 8);
    float4 v0, v1;
    v0.x=eb[0]; v0.y=eb[1]; v0.z=eb[2]; v0.w=eb[3]; eo[0]=v0;
    v1.x=eb[4]; v1.y=eb[5]; v1.z=eb[6]; v1.w=eb[7]; eo[1]=v1;
    float acc = b_lin[0] + x1[n] * W_lin[8];
#pragma unroll
    for (int j = 0; j < 8; ++j) acc += eb[j] * W_lin[j];
    outv[n] = acc > 0.f ? acc : 0.f;
}

// ---------------------------------------------------------------------------
extern "C" void kernel_launch(void* const* d_in, const int* in_sizes, int n_in,
                              void* d_out, int out_size, void* d_ws, size_t ws_size,
                              hipStream_t stream) {
    const float* x      = (const float*)d_in[0];
    const int*   ei     = (const int*)  d_in[1];
    const float* ew     = (const float*)d_in[2];
    const float* x1     = (const float*)d_in[3];
    const float* W1_rel = (const float*)d_in[4];
    const float* b1     = (const float*)d_in[5];
    const float* W1_root= (const float*)d_in[6];
    const float* W2_rel = (const float*)d_in[7];
    const float* b2     = (const float*)d_in[8];
    const float* W2_root= (const float*)d_in[9];
    const float* W_lin  = (const float*)d_in[10];
    const float* b_lin  = (const float*)d_in[11];

    float* ws    = (float*)d_ws;
    unsigned int* y1u = (unsigned int*)ws;              // N*16 uints (bf16 y1, 6.4MB)
    float* agg2  = (float*)ws;                          // N*8 f32 — aliases dead y1
    float* r1    = (float*)(y1u + (size_t)NN * 16);     // N*32
    float* agg1  = r1   + (size_t)NN * 32;              // N*32
    float* y2    = agg1 + (size_t)NN * 32;              // N*8
    float* r2    = y2   + (size_t)NN * 8;               // N*8
    int*   gcursor = (int*)(r2 + (size_t)NN * 8);       // NB, padded to 1024
    int2*  rowptr2 = (int2*)(gcursor + 1024);           // NN int2
    int2*  e_sw    = rowptr2 + NN;                      // NB*CAP int2

    float* outv = (float*)d_out;             // N   (output 0)
    float* emb  = outv + NN;                 // N*8 (output 1)

    hipMemsetAsync(gcursor, 0, NB * sizeof(int), stream);

    int nbN = (NN + 255) / 256;
    k_bucket<<<NBLK, THR, 0, stream>>>(ei, ew, gcursor, e_sw);
    k_sort<<<NB, 1024, 0, stream>>>(gcursor, e_sw, rowptr2);
    k_xform<<<(NN + 63) / 64, 256, 0, stream>>>(x, W1_rel, W1_root, y1u, r1);
    k_reduce1<<<(NN * 8 + 255) / 256, 256, 0, stream>>>(rowptr2, e_sw, y1u, agg1);
    k_node1<<<nbN, 256, 0, stream>>>(agg1, r1, b1, W2_rel, W2_root, y2, r2);
    k_reduce2<<<(NN * 2 + 255) / 256, 256, 0, stream>>>(rowptr2, e_sw, y2, agg2);
    k_final<<<nbN, 256, 0, stream>>>(agg2, r2, x1, b2, W_lin, b_lin, outv, emb);
}

// Round 15
// 187.075 us; speedup vs baseline: 1.5944x; 1.0737x over previous
//
#include <hip/hip_runtime.h>
#include <hip/hip_bf16.h>

constexpr int NN = 100000;   // nodes
constexpr int NE = 3200000;  // edges
constexpr int BSHIFT = 8;                       // 256 dsts per bucket
constexpr int BSPAN  = 1 << BSHIFT;
constexpr int NB = (NN + BSPAN - 1) >> BSHIFT;  // 391 buckets
constexpr int CAP = 12288;                      // mean 8184 real + ~1792 pad, +22 sigma
constexpr int NBLK = 512;                       // bucket blocks (68KB LDS -> 2/CU)
constexpr int THR  = 512;
constexpr int CHUNK = NE / NBLK;                // 6250 edges per block (exact)
constexpr int XPAD = 68;                        // xform LDS row pitch (floats)

// bf16 helpers (RNE)
__device__ __forceinline__ unsigned int bf16pack(float a, float b) {
    unsigned int ua = __float_as_uint(a);
    unsigned int ub = __float_as_uint(b);
    ua += 0x7FFF + ((ua >> 16) & 1);
    ub += 0x7FFF + ((ub >> 16) & 1);
    return (ua >> 16) | (ub & 0xFFFF0000u);
}
__device__ __forceinline__ float bfl(unsigned int u) { return __uint_as_float(u << 16); }
__device__ __forceinline__ float bfh(unsigned int u) { return __uint_as_float(u & 0xFFFF0000u); }

// ---------------------------------------------------------------------------
// Pass A: stage-and-burst coarse bucket sort by dst>>8.
// Round-14 lesson: at 132KB LDS the kernel was 1 block/CU and latency-bound
// (48us for 56MB). Halve CHUNK -> 68KB -> 2 blocks/CU. round8 (64B) exclusive
// segments; burst writes keep lines fully dirty (round-11 lesson).
// Payload: int2 { (dst&255)<<17 | src , bits(w) }; sentinel x=-1.
// ---------------------------------------------------------------------------
__global__ __launch_bounds__(THR) void k_bucket(
    const int* __restrict__ ei, const float* __restrict__ ew,
    int* __restrict__ gcursor, int2* __restrict__ e_sw)
{
    __shared__ int2 stash[CHUNK];                 // 50000 B
    __shared__ unsigned short inv16[CHUNK];       // 12500 B
    __shared__ int h[NB];
    __shared__ int scan[THR];
    __shared__ int off[NB];
    __shared__ int gbase[NB];
    int tid = threadIdx.x;
    int e0 = blockIdx.x * CHUNK;

    for (int b = tid; b < NB; b += THR) h[b] = 0;
    __syncthreads();
#pragma unroll
    for (int k = 0; k <= CHUNK / THR; ++k) {
        int j = tid + k * THR;
        if (j < CHUNK) {
            int e = e0 + j;
            int d = ei[NE + e];
            int2 v;
            v.x = ((d & (BSPAN - 1)) << 17) | ei[e];
            v.y = __float_as_int(ew[e]);
            stash[j] = v;
            atomicAdd(&h[d >> BSHIFT], 1);
        }
    }
    __syncthreads();
    scan[tid] = (tid < NB) ? h[tid] : 0;
    __syncthreads();
    for (int o = 1; o < THR; o <<= 1) {
        int v = (tid >= o) ? scan[tid - o] : 0;
        __syncthreads();
        scan[tid] += v;
        __syncthreads();
    }
    if (tid < NB) {
        int c = h[tid];
        int r = (c + 7) & ~7;                    // 64B-aligned exclusive reservation
        gbase[tid] = r ? atomicAdd(&gcursor[tid], r) : 0;
        off[tid] = scan[tid] - c;
    }
    __syncthreads();
    for (int j = tid; j < CHUNK; j += THR) {
        int b = ei[NE + e0 + j] >> BSHIFT;
        int p = atomicAdd(&off[b], 1);
        inv16[p] = (unsigned short)j;
    }
    __syncthreads();
    for (int i = tid; i < CHUNK; i += THR) {
        int lo = 0, hi = NB - 1;
        while (lo < hi) {
            int mid = (lo + hi) >> 1;
            if (scan[mid] > i) hi = mid; else lo = mid + 1;
        }
        int b = lo;
        int rel = i - (scan[b] - h[b]);
        int2 v = stash[inv16[i]];
        e_sw[(size_t)b * CAP + gbase[b] + rel] = v;
    }
    int2 sv; sv.x = -1; sv.y = 0;
    for (int b = tid; b < NB; b += THR) {
        int c = h[b];
        int r = (c + 7) & ~7;
        for (int p = c; p < r; ++p)
            e_sw[(size_t)b * CAP + gbase[b] + p] = sv;
    }
}

// ---------------------------------------------------------------------------
// Pass B v2 (burst): within-bucket counting sort by dl via LDS stash + rank,
// SEQUENTIAL write-back (compacted: real edges at segment head). Round-14
// lesson: the register-held version's scattered es[p] writes had the same
// partial-line churn as pre-round-11 k_bucket. LDS 126KB, 1024 thr.
// ---------------------------------------------------------------------------
__global__ __launch_bounds__(1024) void k_sort(
    const int* __restrict__ gcursor, int2* __restrict__ e_sw,
    int2* __restrict__ rowptr2)
{
    __shared__ int2 stash[CAP];                   // 98304 B
    __shared__ unsigned short inv16[CAP];         // 24576 B
    __shared__ int hist[BSPAN];
    __shared__ int startp[BSPAN];
    __shared__ int off[BSPAN];
    int b = blockIdx.x, tid = threadIdx.x;
    int cnt = gcursor[b];                 // padded count (incl. sentinels)
    int2* es = e_sw + (size_t)b * CAP;
    if (tid < BSPAN) hist[tid] = 0;
    __syncthreads();
    for (int i = tid; i < cnt; i += 1024) {
        int2 v = es[i];
        stash[i] = v;
        if (v.x >= 0) atomicAdd(&hist[v.x >> 17], 1);
    }
    __syncthreads();
    if (tid < BSPAN) startp[tid] = hist[tid];
    __syncthreads();
    for (int o = 1; o < BSPAN; o <<= 1) {
        int v = (tid < BSPAN && tid >= o) ? startp[tid - o] : 0;
        __syncthreads();
        if (tid < BSPAN) startp[tid] += v;   // inclusive scan
        __syncthreads();
    }
    int d0 = b << BSHIFT;
    if (tid < BSPAN) {
        int beg_rel = startp[tid] - hist[tid];
        off[tid] = beg_rel;
        int d = d0 + tid;
        if (d < NN) {
            int beg = b * CAP + beg_rel;
            int2 rp; rp.x = beg; rp.y = beg + hist[tid];
            rowptr2[d] = rp;
        }
    }
    __syncthreads();
    for (int i = tid; i < cnt; i += 1024) {
        int2 v = stash[i];
        if (v.x >= 0) {
            int p = atomicAdd(&off[v.x >> 17], 1);
            inv16[p] = (unsigned short)i;
        }
    }
    __syncthreads();
    int tot = startp[BSPAN - 1];          // real edges in this bucket
    for (int i = tid; i < tot; i += 1024)
        es[i] = stash[inv16[i]];          // fully sequential write-back
}

// ---------------------------------------------------------------------------
// Fused transform (round-14, unchanged): y1 = bf16(x @ W1_rel.T),
// r1 = x @ W1_root.T. x and W both LDS-staged; W reads wave-uniform.
// ---------------------------------------------------------------------------
__global__ __launch_bounds__(256) void k_xform(
    const float* __restrict__ x, const float* __restrict__ W1_rel,
    const float* __restrict__ W1_root,
    unsigned int* __restrict__ y1u, float* __restrict__ r1)
{
    __shared__ float xt[64 * XPAD];
    __shared__ float wt[64 * 64];
    int tid = threadIdx.x;
    int n0 = blockIdx.x * 64;
    int nend = NN - n0; if (nend > 64) nend = 64;
    for (int i = tid; i < 512; i += 256) {
        float4 a = reinterpret_cast<const float4*>(W1_rel)[i];
        float4 b = reinterpret_cast<const float4*>(W1_root)[i];
        reinterpret_cast<float4*>(wt)[i]       = a;
        reinterpret_cast<float4*>(wt)[i + 512] = b;
    }
    for (int i = tid; i < nend * 16; i += 256) {
        int n = i >> 4, k4 = (i & 15) << 2;
        float4 v = *reinterpret_cast<const float4*>(x + (size_t)(n0 + n) * 64 + k4);
        *reinterpret_cast<float4*>(&xt[n * XPAD + k4]) = v;
    }
    __syncthreads();
    int q = tid >> 6;
    int n = tid & 63;
    if (n >= nend) return;
    const float* Wb = &wt[q * 16 * 64];
    float acc[16];
#pragma unroll
    for (int o = 0; o < 16; ++o) acc[o] = 0.f;
    const float* xrow = &xt[n * XPAD];
#pragma unroll 4
    for (int kt = 0; kt < 16; ++kt) {
        float4 xv = *reinterpret_cast<const float4*>(xrow + kt * 4);
#pragma unroll
        for (int o = 0; o < 16; ++o) {
            const float* w = Wb + o * 64 + kt * 4;
            acc[o] += xv.x * w[0] + xv.y * w[1] + xv.z * w[2] + xv.w * w[3];
        }
    }
    int node = n0 + n;
    if (q < 2) {
        uint4 a, b;
        a.x = bf16pack(acc[0],  acc[1]);  a.y = bf16pack(acc[2],  acc[3]);
        a.z = bf16pack(acc[4],  acc[5]);  a.w = bf16pack(acc[6],  acc[7]);
        b.x = bf16pack(acc[8],  acc[9]);  b.y = bf16pack(acc[10], acc[11]);
        b.z = bf16pack(acc[12], acc[13]); b.w = bf16pack(acc[14], acc[15]);
        unsigned int* dst = y1u + (size_t)node * 16 + q * 8;
        *reinterpret_cast<uint4*>(dst)     = a;
        *reinterpret_cast<uint4*>(dst + 4) = b;
    } else {
        float* dst = r1 + (size_t)node * 32 + (q - 2) * 16;
#pragma unroll
        for (int i = 0; i < 4; ++i) {
            float4 v; v.x = acc[4*i]; v.y = acc[4*i+1]; v.z = acc[4*i+2]; v.w = acc[4*i+3];
            reinterpret_cast<float4*>(dst)[i] = v;
        }
    }
}

// ---------------------------------------------------------------------------
// Reduce pass 1: 8 lanes per dst row; bf16 y1 rows (64B). 8-edge unrolled
// batches (MLP 8), statically indexed, zero-weight tail masking.
// ---------------------------------------------------------------------------
__global__ __launch_bounds__(256) void k_reduce1(
    const int2* __restrict__ rowptr2, const int2* __restrict__ e_sw,
    const unsigned int* __restrict__ y1u, float* __restrict__ agg1)
{
    int idx = blockIdx.x * 256 + threadIdx.x;
    int d = idx >> 3;
    if (d >= NN) return;
    int g = idx & 7;
    int2 rp = rowptr2[d];
    int beg = rp.x, end = rp.y;
    float a0 = 0.f, a1 = 0.f, a2 = 0.f, a3 = 0.f;
    for (int e = beg; e < end; e += 8) {
        int lim = end - 1;
        int2 pp[8];
#pragma unroll
        for (int u = 0; u < 8; ++u) {
            int ee = e + u;
            pp[u] = e_sw[ee < lim ? ee : lim];
        }
        uint2 qq[8];
#pragma unroll
        for (int u = 0; u < 8; ++u)
            qq[u] = *reinterpret_cast<const uint2*>(
                y1u + (size_t)(pp[u].x & 0x1FFFF) * 16 + g * 2);
#pragma unroll
        for (int u = 0; u < 8; ++u) {
            float w = (e + u < end) ? __int_as_float(pp[u].y) : 0.f;
            a0 += bfl(qq[u].x) * w; a1 += bfh(qq[u].x) * w;
            a2 += bfl(qq[u].y) * w; a3 += bfh(qq[u].y) * w;
        }
    }
    float4 o; o.x = a0; o.y = a1; o.z = a2; o.w = a3;
    *reinterpret_cast<float4*>(agg1 + (size_t)d * 32 + g * 4) = o;
}

// ---------------------------------------------------------------------------
// Node pass (light): h = relu(agg1 + r1 + b1); y2 = h@W2_rel.T; r2 = h@W2_root.T
// (unchanged)
// ---------------------------------------------------------------------------
__global__ __launch_bounds__(256) void k_node1(
    const float* __restrict__ agg1, const float* __restrict__ r1,
    const float* __restrict__ b1,
    const float* __restrict__ W2_rel, const float* __restrict__ W2_root,
    float* __restrict__ y2, float* __restrict__ r2)
{
    int n = blockIdx.x * 256 + threadIdx.x;
    if (n >= NN) return;
    float h[32];
    const float4* arow = reinterpret_cast<const float4*>(agg1 + (size_t)n * 32);
    const float4* rrow = reinterpret_cast<const float4*>(r1   + (size_t)n * 32);
#pragma unroll
    for (int og = 0; og < 8; ++og) {
        float4 a = arow[og], r = rrow[og];
        float t0 = a.x + r.x + b1[og*4+0];
        float t1 = a.y + r.y + b1[og*4+1];
        float t2 = a.z + r.z + b1[og*4+2];
        float t3 = a.w + r.w + b1[og*4+3];
        h[og*4+0] = t0 > 0.f ? t0 : 0.f;
        h[og*4+1] = t1 > 0.f ? t1 : 0.f;
        h[og*4+2] = t2 > 0.f ? t2 : 0.f;
        h[og*4+3] = t3 > 0.f ? t3 : 0.f;
    }
    float o2[8], o3[8];
#pragma unroll
    for (int j = 0; j < 8; ++j) {
        const float* wr = W2_rel  + j * 32;
        const float* wo = W2_root + j * 32;
        float s0 = 0.f, s1 = 0.f;
#pragma unroll
        for (int c = 0; c < 32; ++c) { s0 += h[c] * wr[c]; s1 += h[c] * wo[c]; }
        o2[j] = s0; o3[j] = s1;
    }
    float4* y2o = reinterpret_cast<float4*>(y2 + (size_t)n * 8);
    float4* r2o = reinterpret_cast<float4*>(r2 + (size_t)n * 8);
    float4 v0, v1;
    v0.x=o2[0]; v0.y=o2[1]; v0.z=o2[2]; v0.w=o2[3]; y2o[0]=v0;
    v1.x=o2[4]; v1.y=o2[5]; v1.z=o2[6]; v1.w=o2[7]; y2o[1]=v1;
    v0.x=o3[0]; v0.y=o3[1]; v0.z=o3[2]; v0.w=o3[3]; r2o[0]=v0;
    v1.x=o3[4]; v1.y=o3[5]; v1.z=o3[6]; v1.w=o3[7]; r2o[1]=v1;
}

// ---------------------------------------------------------------------------
// Reduce pass 2: 2 lanes per dst row (8 f32 features). (unchanged)
// ---------------------------------------------------------------------------
__global__ __launch_bounds__(256) void k_reduce2(
    const int2* __restrict__ rowptr2, const int2* __restrict__ e_sw,
    const float* __restrict__ y2, float* __restrict__ agg2)
{
    int idx = blockIdx.x * 256 + threadIdx.x;
    int d = idx >> 1;
    if (d >= NN) return;
    int g = idx & 1;
    int2 rp = rowptr2[d];
    int beg = rp.x, end = rp.y;
    float a0 = 0.f, a1 = 0.f, a2 = 0.f, a3 = 0.f;
    for (int e = beg; e < end; e += 4) {
        int eB = e + 1, eC = e + 2, eD = e + 3;
        int lim = end - 1;
        int2 pA = e_sw[e];
        int2 pB = e_sw[eB < lim ? eB : lim];
        int2 pC = e_sw[eC < lim ? eC : lim];
        int2 pD = e_sw[eD < lim ? eD : lim];
        float wA = __int_as_float(pA.y);
        float wB = eB < end ? __int_as_float(pB.y) : 0.f;
        float wC = eC < end ? __int_as_float(pC.y) : 0.f;
        float wD = eD < end ? __int_as_float(pD.y) : 0.f;
        float4 vA = *reinterpret_cast<const float4*>(y2 + (size_t)(pA.x & 0x1FFFF) * 8 + g * 4);
        float4 vB = *reinterpret_cast<const float4*>(y2 + (size_t)(pB.x & 0x1FFFF) * 8 + g * 4);
        float4 vC = *reinterpret_cast<const float4*>(y2 + (size_t)(pC.x & 0x1FFFF) * 8 + g * 4);
        float4 vD = *reinterpret_cast<const float4*>(y2 + (size_t)(pD.x & 0x1FFFF) * 8 + g * 4);
        a0 += vA.x * wA + vB.x * wB + vC.x * wC + vD.x * wD;
        a1 += vA.y * wA + vB.y * wB + vC.y * wC + vD.y * wD;
        a2 += vA.z * wA + vB.z * wB + vC.z * wC + vD.z * wD;
        a3 += vA.w * wA + vB.w * wB + vC.w * wC + vD.w * wD;
    }
    float4 o; o.x = a0; o.y = a1; o.z = a2; o.w = a3;
    *reinterpret_cast<float4*>(agg2 + (size_t)d * 8 + g * 4) = o;
}

// ---------------------------------------------------------------------------
// Final: h2 = agg2 + b2 + r2; emb = log_softmax(h2); out = relu([emb,x1]@W_lin.T+b)
// (unchanged)
// ---------------------------------------------------------------------------
__global__ __launch_bounds__(256) void k_final(
    const float* __restrict__ agg2, const float* __restrict__ r2,
    const float* __restrict__ x1, const float* __restrict__ b2,
    const float* __restrict__ W_lin, const float* __restrict__ b_lin,
    float* __restrict__ outv, float* __restrict__ emb)
{
    int n = blockIdx.x * 256 + threadIdx.x;
    if (n >= NN) return;
    const float4* arow = reinterpret_cast<const float4*>(agg2 + (size_t)n * 8);
    const float4* rrow = reinterpret_cast<const float4*>(r2   + (size_t)n * 8);
    float h2[8];
    {
        float4 a0 = arow[0], a1 = arow[1], r0 = rrow[0], r1v = rrow[1];
        h2[0]=a0.x+r0.x+b2[0]; h2[1]=a0.y+r0.y+b2[1];
        h2[2]=a0.z+r0.z+b2[2]; h2[3]=a0.w+r0.w+b2[3];
        h2[4]=a1.x+r1v.x+b2[4]; h2[5]=a1.y+r1v.y+b2[5];
        h2[6]=a1.z+r1v.z+b2[6]; h2[7]=a1.w+r1v.w+b2[7];
    }
    float m = h2[0];
#pragma unroll
    for (int j = 1; j < 8; ++j) m = fmaxf(m, h2[j]);
    float sum = 0.f;
#pragma unroll
    for (int j = 0; j < 8; ++j) sum += __expf(h2[j] - m);
    float lse = __logf(sum);
    float eb[8];
#pragma unroll
    for (int j = 0; j < 8; ++j) eb[j] = h2[j] - m - lse;
    float4* eo = reinterpret_cast<float4*>(emb + (size_t)n * 8);
    float4 v0, v1;
    v0.x=eb[0]; v0.y=eb[1]; v0.z=eb[2]; v0.w=eb[3]; eo[0]=v0;
    v1.x=eb[4]; v1.y=eb[5]; v1.z=eb[6]; v1.w=eb[7]; eo[1]=v1;
    float acc = b_lin[0] + x1[n] * W_lin[8];
#pragma unroll
    for (int j = 0; j < 8; ++j) acc += eb[j] * W_lin[j];
    outv[n] = acc > 0.f ? acc : 0.f;
}

// ---------------------------------------------------------------------------
extern "C" void kernel_launch(void* const* d_in, const int* in_sizes, int n_in,
                              void* d_out, int out_size, void* d_ws, size_t ws_size,
                              hipStream_t stream) {
    const float* x      = (const float*)d_in[0];
    const int*   ei     = (const int*)  d_in[1];
    const float* ew     = (const float*)d_in[2];
    const float* x1     = (const float*)d_in[3];
    const float* W1_rel = (const float*)d_in[4];
    const float* b1     = (const float*)d_in[5];
    const float* W1_root= (const float*)d_in[6];
    const float* W2_rel = (const float*)d_in[7];
    const float* b2     = (const float*)d_in[8];
    const float* W2_root= (const float*)d_in[9];
    const float* W_lin  = (const float*)d_in[10];
    const float* b_lin  = (const float*)d_in[11];

    float* ws    = (float*)d_ws;
    unsigned int* y1u = (unsigned int*)ws;              // N*16 uints (bf16 y1, 6.4MB)
    float* agg2  = (float*)ws;                          // N*8 f32 — aliases dead y1
    float* r1    = (float*)(y1u + (size_t)NN * 16);     // N*32
    float* agg1  = r1   + (size_t)NN * 32;              // N*32
    float* y2    = agg1 + (size_t)NN * 32;              // N*8
    float* r2    = y2   + (size_t)NN * 8;               // N*8
    int*   gcursor = (int*)(r2 + (size_t)NN * 8);       // NB, padded to 1024
    int2*  rowptr2 = (int2*)(gcursor + 1024);           // NN int2
    int2*  e_sw    = rowptr2 + NN;                      // NB*CAP int2

    float* outv = (float*)d_out;             // N   (output 0)
    float* emb  = outv + NN;                 // N*8 (output 1)

    hipMemsetAsync(gcursor, 0, NB * sizeof(int), stream);

    int nbN = (NN + 255) / 256;
    k_bucket<<<NBLK, THR, 0, stream>>>(ei, ew, gcursor, e_sw);
    k_sort<<<NB, 1024, 0, stream>>>(gcursor, e_sw, rowptr2);
    k_xform<<<(NN + 63) / 64, 256, 0, stream>>>(x, W1_rel, W1_root, y1u, r1);
    k_reduce1<<<(NN * 8 + 255) / 256, 256, 0, stream>>>(rowptr2, e_sw, y1u, agg1);
    k_node1<<<nbN, 256, 0, stream>>>(agg1, r1, b1, W2_rel, W2_root, y2, r2);
    k_reduce2<<<(NN * 2 + 255) / 256, 256, 0, stream>>>(rowptr2, e_sw, y2, agg2);
    k_final<<<nbN, 256, 0, stream>>>(agg2, r2, x1, b2, W_lin, b_lin, outv, emb);
}